// Round 2
// baseline (927.051 us; speedup 1.0000x reference)
//
#include <hip/hip_runtime.h>
#include <hip/hip_bf16.h>

typedef unsigned short u16;
typedef unsigned int u32;
typedef __attribute__((ext_vector_type(8))) short s8v;   // 8 x bf16
typedef __attribute__((ext_vector_type(4))) float f4v;   // mfma acc

__device__ __forceinline__ float b2f(u16 u) {
  union { u32 i; float f; } v; v.i = ((u32)u) << 16; return v.f;
}
__device__ __forceinline__ u16 f2b(float f) {
  union { float f; u32 i; } v; v.f = f;
  u32 r = v.i + 0x7FFFu + ((v.i >> 16) & 1u);
  return (u16)(r >> 16);
}
__device__ __forceinline__ float sigf(float x) { return 1.0f / (1.0f + __expf(-x)); }
__device__ __forceinline__ float tanh_(float x) { return 1.0f - 2.0f / (__expf(2.0f * x) + 1.0f); }

// ---------------- weight conversion fp32 -> bf16 ----------------
struct CvtArgs {
  const float* src[9];
  u16* dst[9];
  int n4[9];
};
__global__ __launch_bounds__(256) void k_cvt(CvtArgs a) {
  int seg = blockIdx.y;
  int i = blockIdx.x * 256 + threadIdx.x;
  if (i >= a.n4[seg]) return;
  float4 v = ((const float4*)a.src[seg])[i];
  ushort4 o;
  o.x = f2b(v.x); o.y = f2b(v.y); o.z = f2b(v.z); o.w = f2b(v.w);
  ((ushort4*)a.dst[seg])[i] = o;
}

// ------- transpose input [B,C,H,W] -> A_h bf16 [(b,w,h)][c]; also channel means -------
__global__ __launch_bounds__(256) void k_tin(const float* __restrict__ in,
                                             u16* __restrict__ A,
                                             float* __restrict__ meansum) {
  int b = blockIdx.z, h = blockIdx.y, c0 = blockIdx.x * 64;
  int t = threadIdx.x, lane = t & 63, q = t >> 6;
  __shared__ u16 lT[64][66];
  const float* src = in + ((b * 256 + c0) * 64 + h) * 64;
#pragma unroll 4
  for (int i = 0; i < 16; ++i) {
    int cl = q * 16 + i;
    float v = src[cl * 4096 + lane];
    lT[cl][lane] = f2b(v);
    float s = v;
#pragma unroll
    for (int off = 32; off; off >>= 1) s += __shfl_xor(s, off);
    if (lane == 0) atomicAdd(&meansum[b * 256 + c0 + cl], s);
  }
  __syncthreads();
  u16* dst = A + (b * 4096 + h) * 256 + c0;
#pragma unroll 4
  for (int i = 0; i < 16; ++i) {
    int w = q * 16 + i;
    dst[w * 16384 + lane] = lT[lane][w];
  }
}

// ------- q_avg[b][o] = softmax_o( Wl[o,:] . mean_c ) -------
__global__ __launch_bounds__(256) void k_qavg(const float* __restrict__ meansum,
                                              const float* __restrict__ Wl,
                                              float* __restrict__ qavg) {
  int b = blockIdx.x, t = threadIdx.x;
  __shared__ float mean[256];
  __shared__ float red[256];
  mean[t] = meansum[b * 256 + t] * (1.0f / 4096.0f);
  __syncthreads();
  const float* wr = Wl + t * 256;
  float acc = 0.0f;
  for (int c = 0; c < 256; ++c) acc = fmaf(wr[c], mean[c], acc);
  red[t] = acc; __syncthreads();
  for (int s = 128; s; s >>= 1) { if (t < s) red[t] = fmaxf(red[t], red[t + s]); __syncthreads(); }
  float mx = red[0]; __syncthreads();
  float e = __expf(acc - mx);
  red[t] = e; __syncthreads();
  for (int s = 128; s; s >>= 1) { if (t < s) red[t] += red[t + s]; __syncthreads(); }
  qavg[b * 256 + t] = e / red[0];
}

// ------- generic bf16 MFMA GEMM: out[m][n] = bf16( sum_k A[m][k]*W[n][k] + bias[n] ) -------
// A: [Mtot][256] bf16, W: [Ntot][256] bf16, out: [Mtot][nstride] bf16. tile 64x64, K=256.
__global__ __launch_bounds__(256) void k_gemm(const u16* __restrict__ A,
                                              const u16* __restrict__ W,
                                              const float* __restrict__ bias0,
                                              const float* __restrict__ bias1,
                                              u16* __restrict__ out, int nstride) {
  int nb = blockIdx.x * 64;
  int mb = blockIdx.y * 64;
  int t = threadIdx.x, lane = t & 63, wid = t >> 6;
  int laneg = lane & 15, lk = lane >> 4;
  __shared__ __align__(16) u16 lA[64][64];
  __shared__ __align__(16) u16 lW[64][64];
  f4v acc[4] = {{0,0,0,0},{0,0,0,0},{0,0,0,0},{0,0,0,0}};
  int srow = t & 63, sk = (t >> 6) * 8;
  const uint4* gA = (const uint4*)(A + (mb + srow) * 256 + sk);
  const uint4* gW = (const uint4*)(W + (nb + srow) * 256 + sk);
  uint4* sA = (uint4*)&lA[srow][sk ^ ((srow & 7) << 3)];
  uint4* sW = (uint4*)&lW[srow][sk ^ ((srow & 7) << 3)];
  for (int kb = 0; kb < 8; ++kb) {
    uint4 va = gA[kb * 4];
    uint4 vw = gW[kb * 4];
    if (kb) __syncthreads();
    *sA = va; *sW = vw;
    __syncthreads();
    int r = wid * 16 + laneg;
    s8v af = *(const s8v*)&lA[r][(lk * 8) ^ ((r & 7) << 3)];
#pragma unroll
    for (int nt = 0; nt < 4; ++nt) {
      int rn = nt * 16 + laneg;
      s8v wf = *(const s8v*)&lW[rn][(lk * 8) ^ ((rn & 7) << 3)];
      acc[nt] = __builtin_amdgcn_mfma_f32_16x16x32_bf16(af, wf, acc[nt], 0, 0, 0);
    }
  }
#pragma unroll
  for (int nt = 0; nt < 4; ++nt) {
    int col = nb + nt * 16 + laneg;
    float bv = 0.0f;
    if (bias0) bv = (col < 512) ? bias0[col] : bias1[col - 512];
    int row0 = mb + wid * 16 + lk * 4;
#pragma unroll
    for (int j = 0; j < 4; ++j)
      out[(row0 + j) * nstride + col] = f2b(acc[nt][j] + bv);
  }
}

// ------- bidirectional LSTM recurrence, MFMA. one kernel for both phases. -------
// pre: bf16 [s*64+t][1024] (cols 0..511 fwd gates i,f,g,o ; 512..1023 bwd)
// Whh2: bf16 [2][512][128]; outb: bf16 [(s/64)*4096 + t*64 + s%64][256] (ch = dir*128+hc)
__global__ __launch_bounds__(256, 1) void k_recur(const u16* __restrict__ pre,
                                                  const u16* __restrict__ Whh2,
                                                  u16* __restrict__ outb) {
  int dir = blockIdx.y;
  int s0 = blockIdx.x << 4;
  int t = threadIdx.x, lane = t & 63, wid = t >> 6;
  int laneg = lane & 15, lk = lane >> 4;
  const u16* Wd = Whh2 + dir * 65536;
  int cb[8];
#pragma unroll
  for (int g = 0; g < 4; ++g)
#pragma unroll
    for (int m = 0; m < 2; ++m)
      cb[g * 2 + m] = g * 128 + wid * 32 + m * 16;
  s8v bfr[8][4];
#pragma unroll
  for (int tau = 0; tau < 8; ++tau)
#pragma unroll
    for (int kk = 0; kk < 4; ++kk)
      bfr[tau][kk] = *(const s8v*)(Wd + (cb[tau] + laneg) * 128 + kk * 32 + lk * 8);
  __shared__ __align__(16) u16 hb[2][16][128];
  for (int i = t; i < 2048; i += 256) ((u16*)hb)[i] = 0;
  float cs[2][4] = {{0,0,0,0},{0,0,0,0}};
  int gofs = dir << 9;
  const u16* pl = pre + (s0 + lk * 4) * 65536 + gofs + laneg;
  int orow0 = ((s0 >> 6) << 12) + (s0 & 63) + lk * 4;
  int chb = (dir << 7) + wid * 32;
  u16 pf[8][4];
  int tc0 = dir ? 63 : 0;
#pragma unroll
  for (int tau = 0; tau < 8; ++tau)
#pragma unroll
    for (int j = 0; j < 4; ++j)
      pf[tau][j] = pl[j * 65536 + tc0 * 1024 + cb[tau]];
  __syncthreads();
  int cur = 0;
  for (int st = 0; st < 64; ++st) {
    int tc = dir ? 63 - st : st;
    f4v acc[8];
#pragma unroll
    for (int tau = 0; tau < 8; ++tau)
#pragma unroll
      for (int j = 0; j < 4; ++j)
        acc[tau][j] = b2f(pf[tau][j]);
    if (st < 63) {
      int tcn = dir ? tc - 1 : tc + 1;
#pragma unroll
      for (int tau = 0; tau < 8; ++tau)
#pragma unroll
        for (int j = 0; j < 4; ++j)
          pf[tau][j] = pl[j * 65536 + tcn * 1024 + cb[tau]];
    }
    s8v afr[4];
#pragma unroll
    for (int kk = 0; kk < 4; ++kk)
      afr[kk] = *(const s8v*)&hb[cur][laneg][(kk * 32 + lk * 8) ^ ((laneg & 7) << 3)];
#pragma unroll
    for (int tau = 0; tau < 8; ++tau)
#pragma unroll
      for (int kk = 0; kk < 4; ++kk)
        acc[tau] = __builtin_amdgcn_mfma_f32_16x16x32_bf16(afr[kk], bfr[tau][kk], acc[tau], 0, 0, 0);
    int nxt = cur ^ 1;
#pragma unroll
    for (int m = 0; m < 2; ++m)
#pragma unroll
      for (int j = 0; j < 4; ++j) {
        float iv = sigf(acc[0 + m][j]);
        float fv = sigf(acc[2 + m][j]);
        float gv = tanh_(acc[4 + m][j]);
        float ov = sigf(acc[6 + m][j]);
        float c = fv * cs[m][j] + iv * gv;
        cs[m][j] = c;
        float hv = ov * tanh_(c);
        u16 hb16 = f2b(hv);
        int row = lk * 4 + j;
        int hcol = wid * 32 + m * 16 + laneg;
        hb[nxt][row][hcol ^ ((row & 7) << 3)] = hb16;
        outb[(orow0 + tc * 64 + j) * 256 + chb + m * 16 + laneg] = hb16;
      }
    __syncthreads();
    cur = nxt;
  }
}

// ------- per-(b,o) max & sumexp over 4096 spatial rows of VF -------
__global__ __launch_bounds__(1024) void k_smr(const u16* __restrict__ VF,
                                              float* __restrict__ mbuf,
                                              float* __restrict__ Zbuf) {
  int b = blockIdx.x;
  int t = threadIdx.x;
  int o = t & 255, q = t >> 8;
  const u16* p = VF + (b * 4096 + q * 1024) * 256 + o;
  float m0 = -1e30f, m1 = -1e30f, m2 = -1e30f, m3 = -1e30f;
  float s0 = 0.f, s1 = 0.f, s2 = 0.f, s3 = 0.f;
  for (int s = 0; s < 1024; s += 4) {
    float x0 = b2f(p[(s + 0) * 256]);
    float x1 = b2f(p[(s + 1) * 256]);
    float x2 = b2f(p[(s + 2) * 256]);
    float x3 = b2f(p[(s + 3) * 256]);
    if (x0 > m0) { s0 = s0 * __expf(m0 - x0) + 1.f; m0 = x0; } else s0 += __expf(x0 - m0);
    if (x1 > m1) { s1 = s1 * __expf(m1 - x1) + 1.f; m1 = x1; } else s1 += __expf(x1 - m1);
    if (x2 > m2) { s2 = s2 * __expf(m2 - x2) + 1.f; m2 = x2; } else s2 += __expf(x2 - m2);
    if (x3 > m3) { s3 = s3 * __expf(m3 - x3) + 1.f; m3 = x3; } else s3 += __expf(x3 - m3);
  }
  float M = fmaxf(fmaxf(m0, m1), fmaxf(m2, m3));
  float S = s0 * __expf(m0 - M) + s1 * __expf(m1 - M) + s2 * __expf(m2 - M) + s3 * __expf(m3 - M);
  __shared__ float pm[4][256], ps[4][256];
  pm[q][o] = M; ps[q][o] = S;
  __syncthreads();
  if (q == 0) {
    float MM = fmaxf(fmaxf(pm[0][o], pm[1][o]), fmaxf(pm[2][o], pm[3][o]));
    float SS = ps[0][o] * __expf(pm[0][o] - MM) + ps[1][o] * __expf(pm[1][o] - MM) +
               ps[2][o] * __expf(pm[2][o] - MM) + ps[3][o] * __expf(pm[3][o] - MM);
    mbuf[b * 256 + o] = MM;
    Zbuf[b * 256 + o] = SS;
  }
}

// ------- attention logits: att[row] = sum_o (qavg[o]/Z[o]) * exp(VF[row][o]-m[o]) -------
__global__ __launch_bounds__(256) void k_att(const u16* __restrict__ VF,
                                             const float* __restrict__ qavg,
                                             const float* __restrict__ mbuf,
                                             const float* __restrict__ Zbuf,
                                             float* __restrict__ att) {
  int bx = blockIdx.x;
  int b = bx >> 6;
  int rowbase = bx * 64;
  int t = threadIdx.x, lane = t & 63, wid = t >> 6;
  __shared__ __align__(16) float lwo[256];
  __shared__ __align__(16) float lmo[256];
  {
    float Z = Zbuf[b * 256 + t];
    lwo[t] = qavg[b * 256 + t] / Z;
    lmo[t] = mbuf[b * 256 + t];
  }
  __syncthreads();
  float4 wo = *(const float4*)&lwo[lane * 4];
  float4 mo = *(const float4*)&lmo[lane * 4];
  for (int i = 0; i < 16; ++i) {
    int row = rowbase + wid * 16 + i;
    uint2 v = *(const uint2*)&VF[row * 256 + lane * 4];
    float x0 = b2f((u16)(v.x & 0xffff)), x1 = b2f((u16)(v.x >> 16));
    float x2 = b2f((u16)(v.y & 0xffff)), x3 = b2f((u16)(v.y >> 16));
    float p = wo.x * __expf(x0 - mo.x) + wo.y * __expf(x1 - mo.y) +
              wo.z * __expf(x2 - mo.z) + wo.w * __expf(x3 - mo.w);
#pragma unroll
    for (int off = 32; off; off >>= 1) p += __shfl_xor(p, off);
    if (lane == 0) att[row] = p;
  }
}

// ------- final: out = in * (1 + alpha * sigmoid(att)) -------
__global__ __launch_bounds__(256) void k_final(const float* __restrict__ in,
                                               const float* __restrict__ att,
                                               const float* __restrict__ alpha,
                                               float* __restrict__ out) {
  float al = alpha[0];
  int stride = gridDim.x * 256;
  for (int i = blockIdx.x * 256 + threadIdx.x; i < 4194304; i += stride) {
    float4 v = ((const float4*)in)[i];
    int flat = i * 4;
    int b = flat >> 20;
    int sp = flat & 4095;
    float4 a4 = *(const float4*)&att[b * 4096 + sp];
    float4 r;
    r.x = v.x * (1.f + al * sigf(a4.x));
    r.y = v.y * (1.f + al * sigf(a4.y));
    r.z = v.z * (1.f + al * sigf(a4.z));
    r.w = v.w * (1.f + al * sigf(a4.w));
    ((float4*)out)[i] = r;
  }
}

extern "C" void kernel_launch(void* const* d_in, const int* in_sizes, int n_in,
                              void* d_out, int out_size, void* d_ws, size_t ws_size,
                              hipStream_t stream) {
  const float* input   = (const float*)d_in[0];
  const float* h_Wih_f = (const float*)d_in[1];
  const float* h_Whh_f = (const float*)d_in[2];
  const float* h_b_f   = (const float*)d_in[3];
  const float* h_Wih_b = (const float*)d_in[4];
  const float* h_Whh_b = (const float*)d_in[5];
  const float* h_b_b   = (const float*)d_in[6];
  const float* v_Wih_f = (const float*)d_in[7];
  const float* v_Whh_f = (const float*)d_in[8];
  const float* v_b_f   = (const float*)d_in[9];
  const float* v_Wih_b = (const float*)d_in[10];
  const float* v_Whh_b = (const float*)d_in[11];
  const float* v_b_b   = (const float*)d_in[12];
  const float* Wr      = (const float*)d_in[13];
  const float* Wl      = (const float*)d_in[14];
  const float* alphap  = (const float*)d_in[15];

  char* ws = (char*)d_ws;
  u16* Ah     = (u16*)(ws + 0);            // 33,554,432 B  (also reused as A_r)
  u16* pre    = (u16*)(ws + 33554432);     // 134,217,728 B (also reused as VF)
  u16* Wh     = (u16*)(ws + 167772160);    // 524,288
  u16* Wv     = (u16*)(ws + 168296448);    // 524,288
  u16* WhhH   = (u16*)(ws + 168820736);    // 262,144
  u16* WhhV   = (u16*)(ws + 169082880);    // 262,144
  u16* Wrb    = (u16*)(ws + 169345024);    // 131,072
  float* meansum = (float*)(ws + 169476096); // 16,384
  float* qavg = (float*)(ws + 169492480);  // 16,384
  float* mbuf = (float*)(ws + 169508864);  // 16,384
  float* Zbuf = (float*)(ws + 169525248);  // 16,384
  float* attb = (float*)(ws + 169541632);  // 262,144
  u16* Av = (u16*)d_out;   // horizontal biLSTM output lives in d_out until the end
  u16* Ar = Ah;
  u16* VF = pre;

  (void)hipMemsetAsync(meansum, 0, 16 * 256 * 4, stream);

  CvtArgs ca;
  ca.src[0] = h_Wih_f; ca.dst[0] = Wh;          ca.n4[0] = 32768;
  ca.src[1] = h_Wih_b; ca.dst[1] = Wh + 131072; ca.n4[1] = 32768;
  ca.src[2] = v_Wih_f; ca.dst[2] = Wv;          ca.n4[2] = 32768;
  ca.src[3] = v_Wih_b; ca.dst[3] = Wv + 131072; ca.n4[3] = 32768;
  ca.src[4] = h_Whh_f; ca.dst[4] = WhhH;         ca.n4[4] = 16384;
  ca.src[5] = h_Whh_b; ca.dst[5] = WhhH + 65536; ca.n4[5] = 16384;
  ca.src[6] = v_Whh_f; ca.dst[6] = WhhV;         ca.n4[6] = 16384;
  ca.src[7] = v_Whh_b; ca.dst[7] = WhhV + 65536; ca.n4[7] = 16384;
  ca.src[8] = Wr;      ca.dst[8] = Wrb;          ca.n4[8] = 16384;
  k_cvt<<<dim3(128, 9), 256, 0, stream>>>(ca);

  k_tin<<<dim3(4, 64, 16), 256, 0, stream>>>(input, Ah, meansum);
  k_qavg<<<16, 256, 0, stream>>>(meansum, Wl, qavg);

  k_gemm<<<dim3(16, 1024), 256, 0, stream>>>(Ah, Wh, h_b_f, h_b_b, pre, 1024);
  k_recur<<<dim3(64, 2), 256, 0, stream>>>(pre, WhhH, Av);
  k_gemm<<<dim3(16, 1024), 256, 0, stream>>>(Av, Wv, v_b_f, v_b_b, pre, 1024);
  k_recur<<<dim3(64, 2), 256, 0, stream>>>(pre, WhhV, Ar);
  k_gemm<<<dim3(4, 1024), 256, 0, stream>>>(Ar, Wrb, nullptr, nullptr, VF, 256);

  k_smr<<<16, 1024, 0, stream>>>(VF, mbuf, Zbuf);
  k_att<<<1024, 256, 0, stream>>>(VF, qavg, mbuf, Zbuf, attb);
  k_final<<<2048, 256, 0, stream>>>(input, attb, alphap, (float*)d_out);
}

// Round 3
// 594.457 us; speedup vs baseline: 1.5595x; 1.5595x over previous
//
#include <hip/hip_runtime.h>
#include <hip/hip_bf16.h>

typedef unsigned short u16;
typedef unsigned int u32;
typedef __attribute__((ext_vector_type(8))) short s8v;   // 8 x bf16
typedef __attribute__((ext_vector_type(4))) float f4v;   // mfma acc

__device__ __forceinline__ float b2f(u16 u) {
  union { u32 i; float f; } v; v.i = ((u32)u) << 16; return v.f;
}
__device__ __forceinline__ u16 f2b(float f) {
  union { float f; u32 i; } v; v.f = f;
  u32 r = v.i + 0x7FFFu + ((v.i >> 16) & 1u);
  return (u16)(r >> 16);
}
__device__ __forceinline__ float sigf(float x) { return 1.0f / (1.0f + __expf(-x)); }
__device__ __forceinline__ float tanh_(float x) { return 1.0f - 2.0f / (__expf(2.0f * x) + 1.0f); }

__device__ __forceinline__ void gl_lds16(const u16* g, u16* l) {
  __builtin_amdgcn_global_load_lds(
      (const __attribute__((address_space(1))) u32*)g,
      (__attribute__((address_space(3))) u32*)l, 16, 0, 0);
}

// ---------------- weight conversion fp32 -> bf16 ----------------
struct CvtArgs {
  const float* src[9];
  u16* dst[9];
  int n4[9];
};
__global__ __launch_bounds__(256) void k_cvt(CvtArgs a) {
  int seg = blockIdx.y;
  int i = blockIdx.x * 256 + threadIdx.x;
  if (i >= a.n4[seg]) return;
  float4 v = ((const float4*)a.src[seg])[i];
  ushort4 o;
  o.x = f2b(v.x); o.y = f2b(v.y); o.z = f2b(v.z); o.w = f2b(v.w);
  ((ushort4*)a.dst[seg])[i] = o;
}

// ------- transpose input [B,C,H,W] -> A_h bf16 [(b,w,h)][c]; also channel means -------
__global__ __launch_bounds__(256) void k_tin(const float* __restrict__ in,
                                             u16* __restrict__ A,
                                             float* __restrict__ meansum) {
  int b = blockIdx.z, h = blockIdx.y, c0 = blockIdx.x * 64;
  int t = threadIdx.x, lane = t & 63, q = t >> 6;
  __shared__ u16 lT[64][66];
  const float* src = in + ((b * 256 + c0) * 64 + h) * 64;
#pragma unroll 4
  for (int i = 0; i < 16; ++i) {
    int cl = q * 16 + i;
    float v = src[cl * 4096 + lane];
    lT[cl][lane] = f2b(v);
    float s = v;
#pragma unroll
    for (int off = 32; off; off >>= 1) s += __shfl_xor(s, off);
    if (lane == 0) atomicAdd(&meansum[b * 256 + c0 + cl], s);
  }
  __syncthreads();
  u16* dst = A + (b * 4096 + h) * 256 + c0;
#pragma unroll 4
  for (int i = 0; i < 16; ++i) {
    int w = q * 16 + i;
    dst[w * 16384 + lane] = lT[lane][w];
  }
}

// ------- q_avg[b][o] = softmax_o( Wl[o,:] . mean_c ) -------
__global__ __launch_bounds__(256) void k_qavg(const float* __restrict__ meansum,
                                              const float* __restrict__ Wl,
                                              float* __restrict__ qavg) {
  int b = blockIdx.x, t = threadIdx.x;
  __shared__ float mean[256];
  __shared__ float red[256];
  mean[t] = meansum[b * 256 + t] * (1.0f / 4096.0f);
  __syncthreads();
  const float* wr = Wl + t * 256;
  float acc = 0.0f;
  for (int c = 0; c < 256; ++c) acc = fmaf(wr[c], mean[c], acc);
  red[t] = acc; __syncthreads();
  for (int s = 128; s; s >>= 1) { if (t < s) red[t] = fmaxf(red[t], red[t + s]); __syncthreads(); }
  float mx = red[0]; __syncthreads();
  float e = __expf(acc - mx);
  red[t] = e; __syncthreads();
  for (int s = 128; s; s >>= 1) { if (t < s) red[t] += red[t + s]; __syncthreads(); }
  qavg[b * 256 + t] = e / red[0];
}

// ------- 128x128-tile bf16 MFMA GEMM (m97 structure, gload_lds + XOR swizzle) -------
// A:[Mtot][256], W:[Ntot][256], out[m][n]=bf16(sum_k A[m][k]W[n][k] + bias[n]).
// 1D grid MT*NT blocks, bijective XCD swizzle; 4 waves each own 64x64.
__global__ __launch_bounds__(256, 4) void k_gemm2(const u16* __restrict__ A,
                                                  const u16* __restrict__ W,
                                                  const float* __restrict__ bias0,
                                                  const float* __restrict__ bias1,
                                                  u16* __restrict__ out, int nstride, int NT) {
  int nwg = gridDim.x;
  int q = nwg >> 3;
  int bid = blockIdx.x;
  int swz = (bid & 7) * q + (bid >> 3);
  int mt = swz / NT, nt = swz % NT;
  int mb = mt << 7, nb = nt << 7;
  int t = threadIdx.x, lane = t & 63, wid = t >> 6;
  int laneg = lane & 15, lk = lane >> 4;
  __shared__ __align__(16) u16 lA[128][64];
  __shared__ __align__(16) u16 lW[128][64];
  f4v acc[4][4] = {};
  int wm = wid >> 1, wn = wid & 1;
  for (int kb = 0; kb < 4; ++kb) {
    if (kb) __syncthreads();
#pragma unroll
    for (int k = 0; k < 4; ++k) {
      int rb = (wid << 5) + (k << 3);          // wave-uniform row base (8 rows/instr)
      int r = rb + (lane >> 3);                // this lane's row
      int cs = (lane & 7) ^ (r & 7);           // inverse-swizzled source chunk
      const u16* ga = A + (mb + r) * 256 + (kb << 6) + (cs << 3);
      const u16* gw = W + (nb + r) * 256 + (kb << 6) + (cs << 3);
      gl_lds16(ga, &lA[rb][0]);
      gl_lds16(gw, &lW[rb][0]);
    }
    __syncthreads();
#pragma unroll
    for (int kk = 0; kk < 2; ++kk) {
      s8v af[4], bf[4];
#pragma unroll
      for (int m = 0; m < 4; ++m) {
        int r = (wm << 6) + (m << 4) + laneg;
        int c = ((kk << 2) + lk) ^ (r & 7);
        af[m] = *(const s8v*)&lA[r][c << 3];
      }
#pragma unroll
      for (int n = 0; n < 4; ++n) {
        int r = (wn << 6) + (n << 4) + laneg;
        int c = ((kk << 2) + lk) ^ (r & 7);
        bf[n] = *(const s8v*)&lW[r][c << 3];
      }
#pragma unroll
      for (int m = 0; m < 4; ++m)
#pragma unroll
        for (int n = 0; n < 4; ++n)
          acc[m][n] = __builtin_amdgcn_mfma_f32_16x16x32_bf16(af[m], bf[n], acc[m][n], 0, 0, 0);
    }
  }
#pragma unroll
  for (int m = 0; m < 4; ++m) {
    int row0 = mb + (wm << 6) + (m << 4) + (lk << 2);
#pragma unroll
    for (int n = 0; n < 4; ++n) {
      int col = nb + (wn << 6) + (n << 4) + laneg;
      float bv = 0.0f;
      if (bias0) bv = (col < 512) ? bias0[col] : bias1[col - 512];
#pragma unroll
      for (int j = 0; j < 4; ++j)
        out[(row0 + j) * nstride + col] = f2b(acc[m][n][j] + bv);
    }
  }
}

// ------- bidirectional LSTM recurrence, MFMA. one kernel for both phases. -------
__global__ __launch_bounds__(256, 1) void k_recur(const u16* __restrict__ pre,
                                                  const u16* __restrict__ Whh2,
                                                  u16* __restrict__ outb) {
  int dir = blockIdx.y;
  int s0 = blockIdx.x << 4;
  int t = threadIdx.x, lane = t & 63, wid = t >> 6;
  int laneg = lane & 15, lk = lane >> 4;
  const u16* Wd = Whh2 + dir * 65536;
  int cb[8];
#pragma unroll
  for (int g = 0; g < 4; ++g)
#pragma unroll
    for (int m = 0; m < 2; ++m)
      cb[g * 2 + m] = g * 128 + wid * 32 + m * 16;
  s8v bfr[8][4];
#pragma unroll
  for (int tau = 0; tau < 8; ++tau)
#pragma unroll
    for (int kk = 0; kk < 4; ++kk)
      bfr[tau][kk] = *(const s8v*)(Wd + (cb[tau] + laneg) * 128 + kk * 32 + lk * 8);
  __shared__ __align__(16) u16 hb[2][16][128];
  for (int i = t; i < 2048; i += 256) ((u16*)hb)[i] = 0;
  float cs[2][4] = {{0,0,0,0},{0,0,0,0}};
  int gofs = dir << 9;
  const u16* pl = pre + (s0 + lk * 4) * 65536 + gofs + laneg;
  int orow0 = ((s0 >> 6) << 12) + (s0 & 63) + lk * 4;
  int chb = (dir << 7) + wid * 32;
  u16 pf[8][4];
  int tc0 = dir ? 63 : 0;
#pragma unroll
  for (int tau = 0; tau < 8; ++tau)
#pragma unroll
    for (int j = 0; j < 4; ++j)
      pf[tau][j] = pl[j * 65536 + tc0 * 1024 + cb[tau]];
  __syncthreads();
  int cur = 0;
  for (int st = 0; st < 64; ++st) {
    int tc = dir ? 63 - st : st;
    f4v acc[8];
#pragma unroll
    for (int tau = 0; tau < 8; ++tau)
#pragma unroll
      for (int j = 0; j < 4; ++j)
        acc[tau][j] = b2f(pf[tau][j]);
    if (st < 63) {
      int tcn = dir ? tc - 1 : tc + 1;
#pragma unroll
      for (int tau = 0; tau < 8; ++tau)
#pragma unroll
        for (int j = 0; j < 4; ++j)
          pf[tau][j] = pl[j * 65536 + tcn * 1024 + cb[tau]];
    }
    s8v afr[4];
#pragma unroll
    for (int kk = 0; kk < 4; ++kk)
      afr[kk] = *(const s8v*)&hb[cur][laneg][(kk * 32 + lk * 8) ^ ((laneg & 7) << 3)];
#pragma unroll
    for (int tau = 0; tau < 8; ++tau)
#pragma unroll
      for (int kk = 0; kk < 4; ++kk)
        acc[tau] = __builtin_amdgcn_mfma_f32_16x16x32_bf16(afr[kk], bfr[tau][kk], acc[tau], 0, 0, 0);
    int nxt = cur ^ 1;
#pragma unroll
    for (int m = 0; m < 2; ++m)
#pragma unroll
      for (int j = 0; j < 4; ++j) {
        float iv = sigf(acc[0 + m][j]);
        float fv = sigf(acc[2 + m][j]);
        float gv = tanh_(acc[4 + m][j]);
        float ov = sigf(acc[6 + m][j]);
        float c = fv * cs[m][j] + iv * gv;
        cs[m][j] = c;
        float hv = ov * tanh_(c);
        u16 hb16 = f2b(hv);
        int row = lk * 4 + j;
        int hcol = wid * 32 + m * 16 + laneg;
        hb[nxt][row][hcol ^ ((row & 7) << 3)] = hb16;
        outb[(orow0 + tc * 64 + j) * 256 + chb + m * 16 + laneg] = hb16;
      }
    __syncthreads();
    cur = nxt;
  }
}

// ------- stage 1: per-(b,chunk,o) max & sumexp over 256 rows -------
__global__ __launch_bounds__(256) void k_smr_p(const u16* __restrict__ VF,
                                               float* __restrict__ pm,
                                               float* __restrict__ pZ) {
  int ch = blockIdx.x, b = blockIdx.y;
  int o = threadIdx.x;
  const u16* p = VF + (b * 4096 + ch * 256) * 256 + o;
  float m0 = -1e30f, m1 = -1e30f, m2 = -1e30f, m3 = -1e30f;
  float s0 = 0.f, s1 = 0.f, s2 = 0.f, s3 = 0.f;
  for (int s = 0; s < 256; s += 4) {
    float x0 = b2f(p[(s + 0) * 256]);
    float x1 = b2f(p[(s + 1) * 256]);
    float x2 = b2f(p[(s + 2) * 256]);
    float x3 = b2f(p[(s + 3) * 256]);
    if (x0 > m0) { s0 = s0 * __expf(m0 - x0) + 1.f; m0 = x0; } else s0 += __expf(x0 - m0);
    if (x1 > m1) { s1 = s1 * __expf(m1 - x1) + 1.f; m1 = x1; } else s1 += __expf(x1 - m1);
    if (x2 > m2) { s2 = s2 * __expf(m2 - x2) + 1.f; m2 = x2; } else s2 += __expf(x2 - m2);
    if (x3 > m3) { s3 = s3 * __expf(m3 - x3) + 1.f; m3 = x3; } else s3 += __expf(x3 - m3);
  }
  float M = fmaxf(fmaxf(m0, m1), fmaxf(m2, m3));
  float S = s0 * __expf(m0 - M) + s1 * __expf(m1 - M) + s2 * __expf(m2 - M) + s3 * __expf(m3 - M);
  int idx = (b * 16 + ch) * 256 + o;
  pm[idx] = M; pZ[idx] = S;
}

// ------- stage 2: reduce 16 chunks -------
__global__ __launch_bounds__(256) void k_smr_f(const float* __restrict__ pm,
                                               const float* __restrict__ pZ,
                                               float* __restrict__ mbuf,
                                               float* __restrict__ Zbuf) {
  int b = blockIdx.x, o = threadIdx.x;
  float M = -1e30f;
#pragma unroll
  for (int c = 0; c < 16; ++c) M = fmaxf(M, pm[(b * 16 + c) * 256 + o]);
  float S = 0.f;
#pragma unroll
  for (int c = 0; c < 16; ++c) S += pZ[(b * 16 + c) * 256 + o] * __expf(pm[(b * 16 + c) * 256 + o] - M);
  mbuf[b * 256 + o] = M;
  Zbuf[b * 256 + o] = S;
}

// ------- attention logits: att[row] = sum_o (qavg[o]/Z[o]) * exp(VF[row][o]-m[o]) -------
__global__ __launch_bounds__(256) void k_att(const u16* __restrict__ VF,
                                             const float* __restrict__ qavg,
                                             const float* __restrict__ mbuf,
                                             const float* __restrict__ Zbuf,
                                             float* __restrict__ att) {
  int bx = blockIdx.x;
  int b = bx >> 6;
  int rowbase = bx * 64;
  int t = threadIdx.x, lane = t & 63, wid = t >> 6;
  __shared__ __align__(16) float lwo[256];
  __shared__ __align__(16) float lmo[256];
  {
    float Z = Zbuf[b * 256 + t];
    lwo[t] = qavg[b * 256 + t] / Z;
    lmo[t] = mbuf[b * 256 + t];
  }
  __syncthreads();
  float4 wo = *(const float4*)&lwo[lane * 4];
  float4 mo = *(const float4*)&lmo[lane * 4];
  for (int i = 0; i < 16; ++i) {
    int row = rowbase + wid * 16 + i;
    uint2 v = *(const uint2*)&VF[row * 256 + lane * 4];
    float x0 = b2f((u16)(v.x & 0xffff)), x1 = b2f((u16)(v.x >> 16));
    float x2 = b2f((u16)(v.y & 0xffff)), x3 = b2f((u16)(v.y >> 16));
    float p = wo.x * __expf(x0 - mo.x) + wo.y * __expf(x1 - mo.y) +
              wo.z * __expf(x2 - mo.z) + wo.w * __expf(x3 - mo.w);
#pragma unroll
    for (int off = 32; off; off >>= 1) p += __shfl_xor(p, off);
    if (lane == 0) att[row] = p;
  }
}

// ------- final: out = in * (1 + alpha * sigmoid(att)) -------
__global__ __launch_bounds__(256) void k_final(const float* __restrict__ in,
                                               const float* __restrict__ att,
                                               const float* __restrict__ alpha,
                                               float* __restrict__ out) {
  float al = alpha[0];
  int stride = gridDim.x * 256;
  for (int i = blockIdx.x * 256 + threadIdx.x; i < 4194304; i += stride) {
    float4 v = ((const float4*)in)[i];
    int flat = i * 4;
    int b = flat >> 20;
    int sp = flat & 4095;
    float4 a4 = *(const float4*)&att[b * 4096 + sp];
    float4 r;
    r.x = v.x * (1.f + al * sigf(a4.x));
    r.y = v.y * (1.f + al * sigf(a4.y));
    r.z = v.z * (1.f + al * sigf(a4.z));
    r.w = v.w * (1.f + al * sigf(a4.w));
    ((float4*)out)[i] = r;
  }
}

extern "C" void kernel_launch(void* const* d_in, const int* in_sizes, int n_in,
                              void* d_out, int out_size, void* d_ws, size_t ws_size,
                              hipStream_t stream) {
  const float* input   = (const float*)d_in[0];
  const float* h_Wih_f = (const float*)d_in[1];
  const float* h_Whh_f = (const float*)d_in[2];
  const float* h_b_f   = (const float*)d_in[3];
  const float* h_Wih_b = (const float*)d_in[4];
  const float* h_Whh_b = (const float*)d_in[5];
  const float* h_b_b   = (const float*)d_in[6];
  const float* v_Wih_f = (const float*)d_in[7];
  const float* v_Whh_f = (const float*)d_in[8];
  const float* v_b_f   = (const float*)d_in[9];
  const float* v_Wih_b = (const float*)d_in[10];
  const float* v_Whh_b = (const float*)d_in[11];
  const float* v_b_b   = (const float*)d_in[12];
  const float* Wr      = (const float*)d_in[13];
  const float* Wl      = (const float*)d_in[14];
  const float* alphap  = (const float*)d_in[15];

  char* ws = (char*)d_ws;
  u16* Ah     = (u16*)(ws + 0);            // 33,554,432 B  (also reused as A_r, then pm/pZ)
  u16* pre    = (u16*)(ws + 33554432);     // 134,217,728 B (also reused as VF)
  u16* Wh     = (u16*)(ws + 167772160);    // 524,288
  u16* Wv     = (u16*)(ws + 168296448);    // 524,288
  u16* WhhH   = (u16*)(ws + 168820736);    // 262,144
  u16* WhhV   = (u16*)(ws + 169082880);    // 262,144
  u16* Wrb    = (u16*)(ws + 169345024);    // 131,072
  float* meansum = (float*)(ws + 169476096); // 16,384
  float* qavg = (float*)(ws + 169492480);  // 16,384
  float* mbuf = (float*)(ws + 169508864);  // 16,384
  float* Zbuf = (float*)(ws + 169525248);  // 16,384
  float* attb = (float*)(ws + 169541632);  // 262,144
  u16* Av = (u16*)d_out;   // horizontal biLSTM output lives in d_out until the end
  u16* Ar = Ah;
  u16* VF = pre;
  // pm/pZ partials live in the Ah region (Ar is dead once the Wr-GEMM finished)
  float* pm = (float*)(ws + 0);            // 262,144
  float* pZ = (float*)(ws + 262144);       // 262,144

  (void)hipMemsetAsync(meansum, 0, 16 * 256 * 4, stream);

  CvtArgs ca;
  ca.src[0] = h_Wih_f; ca.dst[0] = Wh;          ca.n4[0] = 32768;
  ca.src[1] = h_Wih_b; ca.dst[1] = Wh + 131072; ca.n4[1] = 32768;
  ca.src[2] = v_Wih_f; ca.dst[2] = Wv;          ca.n4[2] = 32768;
  ca.src[3] = v_Wih_b; ca.dst[3] = Wv + 131072; ca.n4[3] = 32768;
  ca.src[4] = h_Whh_f; ca.dst[4] = WhhH;         ca.n4[4] = 16384;
  ca.src[5] = h_Whh_b; ca.dst[5] = WhhH + 65536; ca.n4[5] = 16384;
  ca.src[6] = v_Whh_f; ca.dst[6] = WhhV;         ca.n4[6] = 16384;
  ca.src[7] = v_Whh_b; ca.dst[7] = WhhV + 65536; ca.n4[7] = 16384;
  ca.src[8] = Wr;      ca.dst[8] = Wrb;          ca.n4[8] = 16384;
  k_cvt<<<dim3(128, 9), 256, 0, stream>>>(ca);

  k_tin<<<dim3(4, 64, 16), 256, 0, stream>>>(input, Ah, meansum);
  k_qavg<<<16, 256, 0, stream>>>(meansum, Wl, qavg);

  k_gemm2<<<4096, 256, 0, stream>>>(Ah, Wh, h_b_f, h_b_b, pre, 1024, 8);
  k_recur<<<dim3(64, 2), 256, 0, stream>>>(pre, WhhH, Av);
  k_gemm2<<<4096, 256, 0, stream>>>(Av, Wv, v_b_f, v_b_b, pre, 1024, 8);
  k_recur<<<dim3(64, 2), 256, 0, stream>>>(pre, WhhV, Ar);
  k_gemm2<<<1024, 256, 0, stream>>>(Ar, Wrb, nullptr, nullptr, VF, 256, 2);

  k_smr_p<<<dim3(16, 16), 256, 0, stream>>>(VF, pm, pZ);
  k_smr_f<<<16, 256, 0, stream>>>(pm, pZ, mbuf, Zbuf);
  k_att<<<1024, 256, 0, stream>>>(VF, qavg, mbuf, Zbuf, attb);
  k_final<<<2048, 256, 0, stream>>>(input, attb, alphap, (float*)d_out);
}

// Round 4
// 460.098 us; speedup vs baseline: 2.0149x; 1.2920x over previous
//
#include <hip/hip_runtime.h>
#include <hip/hip_bf16.h>

typedef unsigned short u16;
typedef unsigned int u32;
typedef __attribute__((ext_vector_type(8))) short s8v;   // 8 x bf16
typedef __attribute__((ext_vector_type(4))) float f4v;   // mfma acc

__device__ __forceinline__ float b2f(u16 u) {
  union { u32 i; float f; } v; v.i = ((u32)u) << 16; return v.f;
}
__device__ __forceinline__ u16 f2b(float f) {
  union { float f; u32 i; } v; v.f = f;
  u32 r = v.i + 0x7FFFu + ((v.i >> 16) & 1u);
  return (u16)(r >> 16);
}
__device__ __forceinline__ float rcpf(float x) { return __builtin_amdgcn_rcpf(x); }
__device__ __forceinline__ float sigf(float x) { return rcpf(1.0f + __expf(-x)); }
__device__ __forceinline__ float tanh_(float x) { return 1.0f - 2.0f * rcpf(__expf(2.0f * x) + 1.0f); }

__device__ __forceinline__ void gl_lds16(const u16* g, u16* l) {
  __builtin_amdgcn_global_load_lds(
      (const __attribute__((address_space(1))) u32*)g,
      (__attribute__((address_space(3))) u32*)l, 16, 0, 0);
}

// LDS-only barrier: waits own-wave DS ops, does NOT drain vmcnt (prefetch stays in flight)
__device__ __forceinline__ void bar_lds() {
  asm volatile("s_waitcnt lgkmcnt(0)" ::: "memory");
  __builtin_amdgcn_s_barrier();
}

// ---------------- weight conversion fp32 -> bf16 ----------------
struct CvtArgs {
  const float* src[9];
  u16* dst[9];
  int n4[9];
};
__global__ __launch_bounds__(256) void k_cvt(CvtArgs a) {
  int seg = blockIdx.y;
  int i = blockIdx.x * 256 + threadIdx.x;
  if (i >= a.n4[seg]) return;
  float4 v = ((const float4*)a.src[seg])[i];
  ushort4 o;
  o.x = f2b(v.x); o.y = f2b(v.y); o.z = f2b(v.z); o.w = f2b(v.w);
  ((ushort4*)a.dst[seg])[i] = o;
}

// ------- transpose input [B,C,H,W] -> A_h bf16 [(b,w,h)][c]; also channel means -------
__global__ __launch_bounds__(256) void k_tin(const float* __restrict__ in,
                                             u16* __restrict__ A,
                                             float* __restrict__ meansum) {
  int b = blockIdx.z, h = blockIdx.y, c0 = blockIdx.x * 64;
  int t = threadIdx.x, lane = t & 63, q = t >> 6;
  __shared__ u16 lT[64][66];
  const float* src = in + ((b * 256 + c0) * 64 + h) * 64;
#pragma unroll 4
  for (int i = 0; i < 16; ++i) {
    int cl = q * 16 + i;
    float v = src[cl * 4096 + lane];
    lT[cl][lane] = f2b(v);
    float s = v;
#pragma unroll
    for (int off = 32; off; off >>= 1) s += __shfl_xor(s, off);
    if (lane == 0) atomicAdd(&meansum[b * 256 + c0 + cl], s);
  }
  __syncthreads();
  u16* dst = A + (b * 4096 + h) * 256 + c0;
#pragma unroll 4
  for (int i = 0; i < 16; ++i) {
    int w = q * 16 + i;
    dst[w * 16384 + lane] = lT[lane][w];
  }
}

// ------- q_avg[b][o] = softmax_o( Wl[o,:] . mean_c ) -------
__global__ __launch_bounds__(256) void k_qavg(const float* __restrict__ meansum,
                                              const float* __restrict__ Wl,
                                              float* __restrict__ qavg) {
  int b = blockIdx.x, t = threadIdx.x;
  __shared__ float mean[256];
  __shared__ float red[256];
  mean[t] = meansum[b * 256 + t] * (1.0f / 4096.0f);
  __syncthreads();
  const float* wr = Wl + t * 256;
  float acc = 0.0f;
  for (int c = 0; c < 256; ++c) acc = fmaf(wr[c], mean[c], acc);
  red[t] = acc; __syncthreads();
  for (int s = 128; s; s >>= 1) { if (t < s) red[t] = fmaxf(red[t], red[t + s]); __syncthreads(); }
  float mx = red[0]; __syncthreads();
  float e = __expf(acc - mx);
  red[t] = e; __syncthreads();
  for (int s = 128; s; s >>= 1) { if (t < s) red[t] += red[t + s]; __syncthreads(); }
  qavg[b * 256 + t] = e / red[0];
}

// ------- 128x128-tile bf16 MFMA GEMM (m97 structure, gload_lds + XOR swizzle) -------
__global__ __launch_bounds__(256, 4) void k_gemm2(const u16* __restrict__ A,
                                                  const u16* __restrict__ W,
                                                  const float* __restrict__ bias0,
                                                  const float* __restrict__ bias1,
                                                  u16* __restrict__ out, int nstride, int NT) {
  int nwg = gridDim.x;
  int q = nwg >> 3;
  int bid = blockIdx.x;
  int swz = (bid & 7) * q + (bid >> 3);
  int mt = swz / NT, nt = swz % NT;
  int mb = mt << 7, nb = nt << 7;
  int t = threadIdx.x, lane = t & 63, wid = t >> 6;
  int laneg = lane & 15, lk = lane >> 4;
  __shared__ __align__(16) u16 lA[128][64];
  __shared__ __align__(16) u16 lW[128][64];
  f4v acc[4][4] = {};
  int wm = wid >> 1, wn = wid & 1;
  for (int kb = 0; kb < 4; ++kb) {
    if (kb) __syncthreads();
#pragma unroll
    for (int k = 0; k < 4; ++k) {
      int rb = (wid << 5) + (k << 3);          // wave-uniform row base (8 rows/instr)
      int r = rb + (lane >> 3);                // this lane's row
      int cs = (lane & 7) ^ (r & 7);           // inverse-swizzled source chunk
      const u16* ga = A + (mb + r) * 256 + (kb << 6) + (cs << 3);
      const u16* gw = W + (nb + r) * 256 + (kb << 6) + (cs << 3);
      gl_lds16(ga, &lA[rb][0]);
      gl_lds16(gw, &lW[rb][0]);
    }
    __syncthreads();
#pragma unroll
    for (int kk = 0; kk < 2; ++kk) {
      s8v af[4], bf[4];
#pragma unroll
      for (int m = 0; m < 4; ++m) {
        int r = (wm << 6) + (m << 4) + laneg;
        int c = ((kk << 2) + lk) ^ (r & 7);
        af[m] = *(const s8v*)&lA[r][c << 3];
      }
#pragma unroll
      for (int n = 0; n < 4; ++n) {
        int r = (wn << 6) + (n << 4) + laneg;
        int c = ((kk << 2) + lk) ^ (r & 7);
        bf[n] = *(const s8v*)&lW[r][c << 3];
      }
#pragma unroll
      for (int m = 0; m < 4; ++m)
#pragma unroll
        for (int n = 0; n < 4; ++n)
          acc[m][n] = __builtin_amdgcn_mfma_f32_16x16x32_bf16(af[m], bf[n], acc[m][n], 0, 0, 0);
    }
  }
#pragma unroll
  for (int m = 0; m < 4; ++m) {
    int row0 = mb + (wm << 6) + (m << 4) + (lk << 2);
#pragma unroll
    for (int n = 0; n < 4; ++n) {
      int col = nb + (wn << 6) + (n << 4) + laneg;
      float bv = 0.0f;
      if (bias0) bv = (col < 512) ? bias0[col] : bias1[col - 512];
#pragma unroll
      for (int j = 0; j < 4; ++j)
        out[(row0 + j) * nstride + col] = f2b(acc[m][n][j] + bv);
    }
  }
}

// ------- bidirectional LSTM recurrence v2: 8 waves x 16 hidden-cols, depth-2 prefetch,
//         LDS-only barrier (vmcnt stays in flight). -------
// pre: bf16 [s*64+t][1024] (cols 0..511 fwd gates i,f,g,o ; 512..1023 bwd)
// Whh2: bf16 [2][512][128]; outb: bf16 [(s/64)*4096 + t*64 + s%64][256] (ch = dir*128+hc)
__global__ __launch_bounds__(512) void k_recur(const u16* __restrict__ pre,
                                               const u16* __restrict__ Whh2,
                                               u16* __restrict__ outb) {
  int dir = blockIdx.y;
  int s0 = blockIdx.x << 4;                 // 16 sequences per block
  int t = threadIdx.x, lane = t & 63, w = t >> 6;  // 8 waves
  int laneg = lane & 15, lk = lane >> 4;
  const u16* Wd = Whh2 + dir * 65536;
  int hc = w << 4;                          // this wave's hidden-col base [hc, hc+16)
  // B-fragments: Whh[gatecol = g*128 + hc + laneg][k]
  s8v bfr[4][4];
#pragma unroll
  for (int g = 0; g < 4; ++g)
#pragma unroll
    for (int kk = 0; kk < 4; ++kk)
      bfr[g][kk] = *(const s8v*)(Wd + (g * 128 + hc + laneg) * 128 + kk * 32 + lk * 8);
  __shared__ __align__(16) u16 hb[2][16][136];   // pitch 136: odd 16B-groups -> ~floor banks
  for (int i = t; i < 2 * 16 * 136; i += 512) ((u16*)hb)[i] = 0;
  float cs[4] = {0.f, 0.f, 0.f, 0.f};
  int tc0 = dir ? 63 : 0;
  int dstep = dir ? -1 : 1;
  const u16* pbase = pre + (dir << 9) + hc + laneg;
  const u16* pA[4];
  const u16* pB[4];
#pragma unroll
  for (int j = 0; j < 4; ++j) {
    int sr = (s0 + lk * 4 + j) * 64;
    pA[j] = pbase + (sr + tc0) * 1024;
    pB[j] = pbase + (sr + tc0 + dstep) * 1024;
  }
  u16 pfA[4][4], pfB[4][4];
#pragma unroll
  for (int g = 0; g < 4; ++g)
#pragma unroll
    for (int j = 0; j < 4; ++j) {
      pfA[g][j] = pA[j][g * 128];
      pfB[g][j] = pB[j][g * 128];
    }
  u16* ob = outb + (((s0 >> 6) << 12) + (s0 & 63) + lk * 4 + tc0 * 64) * 256 + (dir << 7) + hc + laneg;
  long ostep = (long)(dstep * 64) * 256;
  int pstep = dstep * 2048;                 // advance two time-steps (elements)
  __syncthreads();
  int cur = 0;
  auto halfstep = [&](u16 (&pf)[4][4], const u16* (&pb)[4], bool doLoad) {
    f4v acc[4];
#pragma unroll
    for (int g = 0; g < 4; ++g)
#pragma unroll
      for (int j = 0; j < 4; ++j)
        acc[g][j] = b2f(pf[g][j]);
    if (doLoad) {
#pragma unroll
      for (int j = 0; j < 4; ++j) pb[j] += pstep;
#pragma unroll
      for (int g = 0; g < 4; ++g)
#pragma unroll
        for (int j = 0; j < 4; ++j) pf[g][j] = pb[j][g * 128];
    }
    s8v afr[4];
#pragma unroll
    for (int kk = 0; kk < 4; ++kk)
      afr[kk] = *(const s8v*)&hb[cur][laneg][kk * 32 + lk * 8];
#pragma unroll
    for (int g = 0; g < 4; ++g)
#pragma unroll
      for (int kk = 0; kk < 4; ++kk)
        acc[g] = __builtin_amdgcn_mfma_f32_16x16x32_bf16(afr[kk], bfr[g][kk], acc[g], 0, 0, 0);
    int nxt = cur ^ 1;
#pragma unroll
    for (int j = 0; j < 4; ++j) {
      float iv = sigf(acc[0][j]);
      float fv = sigf(acc[1][j]);
      float gv = tanh_(acc[2][j]);
      float ov = sigf(acc[3][j]);
      float c = fv * cs[j] + iv * gv;
      cs[j] = c;
      float hv = ov * tanh_(c);
      u16 hv16 = f2b(hv);
      hb[nxt][lk * 4 + j][hc + laneg] = hv16;
      ob[j * 256] = hv16;
    }
    ob += ostep;
    bar_lds();
    cur = nxt;
  };
  for (int st = 0; st < 64; st += 2) {
    halfstep(pfA, pA, st < 62);   // loads tc(st+2)
    halfstep(pfB, pB, st < 62 - 2 + 2 && st < 61 + 1 ? (st < 61) : false);  // loads tc(st+3): st<=60
  }
}

// ------- stage 1: per-(b,chunk,o) max & sumexp over 256 rows -------
__global__ __launch_bounds__(256) void k_smr_p(const u16* __restrict__ VF,
                                               float* __restrict__ pm,
                                               float* __restrict__ pZ) {
  int ch = blockIdx.x, b = blockIdx.y;
  int o = threadIdx.x;
  const u16* p = VF + (b * 4096 + ch * 256) * 256 + o;
  float m0 = -1e30f, m1 = -1e30f, m2 = -1e30f, m3 = -1e30f;
  float s0 = 0.f, s1 = 0.f, s2 = 0.f, s3 = 0.f;
  for (int s = 0; s < 256; s += 4) {
    float x0 = b2f(p[(s + 0) * 256]);
    float x1 = b2f(p[(s + 1) * 256]);
    float x2 = b2f(p[(s + 2) * 256]);
    float x3 = b2f(p[(s + 3) * 256]);
    if (x0 > m0) { s0 = s0 * __expf(m0 - x0) + 1.f; m0 = x0; } else s0 += __expf(x0 - m0);
    if (x1 > m1) { s1 = s1 * __expf(m1 - x1) + 1.f; m1 = x1; } else s1 += __expf(x1 - m1);
    if (x2 > m2) { s2 = s2 * __expf(m2 - x2) + 1.f; m2 = x2; } else s2 += __expf(x2 - m2);
    if (x3 > m3) { s3 = s3 * __expf(m3 - x3) + 1.f; m3 = x3; } else s3 += __expf(x3 - m3);
  }
  float M = fmaxf(fmaxf(m0, m1), fmaxf(m2, m3));
  float S = s0 * __expf(m0 - M) + s1 * __expf(m1 - M) + s2 * __expf(m2 - M) + s3 * __expf(m3 - M);
  int idx = (b * 16 + ch) * 256 + o;
  pm[idx] = M; pZ[idx] = S;
}

// ------- stage 2: reduce 16 chunks -------
__global__ __launch_bounds__(256) void k_smr_f(const float* __restrict__ pm,
                                               const float* __restrict__ pZ,
                                               float* __restrict__ mbuf,
                                               float* __restrict__ Zbuf) {
  int b = blockIdx.x, o = threadIdx.x;
  float M = -1e30f;
#pragma unroll
  for (int c = 0; c < 16; ++c) M = fmaxf(M, pm[(b * 16 + c) * 256 + o]);
  float S = 0.f;
#pragma unroll
  for (int c = 0; c < 16; ++c) S += pZ[(b * 16 + c) * 256 + o] * __expf(pm[(b * 16 + c) * 256 + o] - M);
  mbuf[b * 256 + o] = M;
  Zbuf[b * 256 + o] = S;
}

// ------- attention logits: att[row] = sum_o (qavg[o]/Z[o]) * exp(VF[row][o]-m[o]) -------
__global__ __launch_bounds__(256) void k_att(const u16* __restrict__ VF,
                                             const float* __restrict__ qavg,
                                             const float* __restrict__ mbuf,
                                             const float* __restrict__ Zbuf,
                                             float* __restrict__ att) {
  int bx = blockIdx.x;
  int b = bx >> 6;
  int rowbase = bx * 64;
  int t = threadIdx.x, lane = t & 63, wid = t >> 6;
  __shared__ __align__(16) float lwo[256];
  __shared__ __align__(16) float lmo[256];
  {
    float Z = Zbuf[b * 256 + t];
    lwo[t] = qavg[b * 256 + t] / Z;
    lmo[t] = mbuf[b * 256 + t];
  }
  __syncthreads();
  float4 wo = *(const float4*)&lwo[lane * 4];
  float4 mo = *(const float4*)&lmo[lane * 4];
  for (int i = 0; i < 16; ++i) {
    int row = rowbase + wid * 16 + i;
    uint2 v = *(const uint2*)&VF[row * 256 + lane * 4];
    float x0 = b2f((u16)(v.x & 0xffff)), x1 = b2f((u16)(v.x >> 16));
    float x2 = b2f((u16)(v.y & 0xffff)), x3 = b2f((u16)(v.y >> 16));
    float p = wo.x * __expf(x0 - mo.x) + wo.y * __expf(x1 - mo.y) +
              wo.z * __expf(x2 - mo.z) + wo.w * __expf(x3 - mo.w);
#pragma unroll
    for (int off = 32; off; off >>= 1) p += __shfl_xor(p, off);
    if (lane == 0) att[row] = p;
  }
}

// ------- final: out = in * (1 + alpha * sigmoid(att)) -------
__global__ __launch_bounds__(256) void k_final(const float* __restrict__ in,
                                               const float* __restrict__ att,
                                               const float* __restrict__ alpha,
                                               float* __restrict__ out) {
  float al = alpha[0];
  int stride = gridDim.x * 256;
  for (int i = blockIdx.x * 256 + threadIdx.x; i < 4194304; i += stride) {
    float4 v = ((const float4*)in)[i];
    int flat = i * 4;
    int b = flat >> 20;
    int sp = flat & 4095;
    float4 a4 = *(const float4*)&att[b * 4096 + sp];
    float4 r;
    r.x = v.x * (1.f + al * sigf(a4.x));
    r.y = v.y * (1.f + al * sigf(a4.y));
    r.z = v.z * (1.f + al * sigf(a4.z));
    r.w = v.w * (1.f + al * sigf(a4.w));
    ((float4*)out)[i] = r;
  }
}

extern "C" void kernel_launch(void* const* d_in, const int* in_sizes, int n_in,
                              void* d_out, int out_size, void* d_ws, size_t ws_size,
                              hipStream_t stream) {
  const float* input   = (const float*)d_in[0];
  const float* h_Wih_f = (const float*)d_in[1];
  const float* h_Whh_f = (const float*)d_in[2];
  const float* h_b_f   = (const float*)d_in[3];
  const float* h_Wih_b = (const float*)d_in[4];
  const float* h_Whh_b = (const float*)d_in[5];
  const float* h_b_b   = (const float*)d_in[6];
  const float* v_Wih_f = (const float*)d_in[7];
  const float* v_Whh_f = (const float*)d_in[8];
  const float* v_b_f   = (const float*)d_in[9];
  const float* v_Wih_b = (const float*)d_in[10];
  const float* v_Whh_b = (const float*)d_in[11];
  const float* v_b_b   = (const float*)d_in[12];
  const float* Wr      = (const float*)d_in[13];
  const float* Wl      = (const float*)d_in[14];
  const float* alphap  = (const float*)d_in[15];

  char* ws = (char*)d_ws;
  u16* Ah     = (u16*)(ws + 0);            // 33,554,432 B  (also reused as A_r, then pm/pZ)
  u16* pre    = (u16*)(ws + 33554432);     // 134,217,728 B (also reused as VF)
  u16* Wh     = (u16*)(ws + 167772160);    // 524,288
  u16* Wv     = (u16*)(ws + 168296448);    // 524,288
  u16* WhhH   = (u16*)(ws + 168820736);    // 262,144
  u16* WhhV   = (u16*)(ws + 169082880);    // 262,144
  u16* Wrb    = (u16*)(ws + 169345024);    // 131,072
  float* meansum = (float*)(ws + 169476096); // 16,384
  float* qavg = (float*)(ws + 169492480);  // 16,384
  float* mbuf = (float*)(ws + 169508864);  // 16,384
  float* Zbuf = (float*)(ws + 169525248);  // 16,384
  float* attb = (float*)(ws + 169541632);  // 262,144
  u16* Av = (u16*)d_out;   // horizontal biLSTM output lives in d_out until the end
  u16* Ar = Ah;
  u16* VF = pre;
  float* pm = (float*)(ws + 0);            // 262,144 (Ah region, dead by then)
  float* pZ = (float*)(ws + 262144);       // 262,144

  (void)hipMemsetAsync(meansum, 0, 16 * 256 * 4, stream);

  CvtArgs ca;
  ca.src[0] = h_Wih_f; ca.dst[0] = Wh;          ca.n4[0] = 32768;
  ca.src[1] = h_Wih_b; ca.dst[1] = Wh + 131072; ca.n4[1] = 32768;
  ca.src[2] = v_Wih_f; ca.dst[2] = Wv;          ca.n4[2] = 32768;
  ca.src[3] = v_Wih_b; ca.dst[3] = Wv + 131072; ca.n4[3] = 32768;
  ca.src[4] = h_Whh_f; ca.dst[4] = WhhH;         ca.n4[4] = 16384;
  ca.src[5] = h_Whh_b; ca.dst[5] = WhhH + 65536; ca.n4[5] = 16384;
  ca.src[6] = v_Whh_f; ca.dst[6] = WhhV;         ca.n4[6] = 16384;
  ca.src[7] = v_Whh_b; ca.dst[7] = WhhV + 65536; ca.n4[7] = 16384;
  ca.src[8] = Wr;      ca.dst[8] = Wrb;          ca.n4[8] = 16384;
  k_cvt<<<dim3(128, 9), 256, 0, stream>>>(ca);

  k_tin<<<dim3(4, 64, 16), 256, 0, stream>>>(input, Ah, meansum);
  k_qavg<<<16, 256, 0, stream>>>(meansum, Wl, qavg);

  k_gemm2<<<4096, 256, 0, stream>>>(Ah, Wh, h_b_f, h_b_b, pre, 1024, 8);
  k_recur<<<dim3(64, 2), 512, 0, stream>>>(pre, WhhH, Av);
  k_gemm2<<<4096, 256, 0, stream>>>(Av, Wv, v_b_f, v_b_b, pre, 1024, 8);
  k_recur<<<dim3(64, 2), 512, 0, stream>>>(pre, WhhV, Ar);
  k_gemm2<<<1024, 256, 0, stream>>>(Ar, Wrb, nullptr, nullptr, VF, 256, 2);

  k_smr_p<<<dim3(16, 16), 256, 0, stream>>>(VF, pm, pZ);
  k_smr_f<<<16, 256, 0, stream>>>(pm, pZ, mbuf, Zbuf);
  k_att<<<1024, 256, 0, stream>>>(VF, qavg, mbuf, Zbuf, attb);
  k_final<<<2048, 256, 0, stream>>>(input, attb, alphap, (float*)d_out);
}

// Round 5
// 443.692 us; speedup vs baseline: 2.0894x; 1.0370x over previous
//
#include <hip/hip_runtime.h>
#include <hip/hip_bf16.h>

typedef unsigned short u16;
typedef unsigned int u32;
typedef __attribute__((ext_vector_type(8))) short s8v;   // 8 x bf16
typedef __attribute__((ext_vector_type(4))) float f4v;   // mfma acc

__device__ __forceinline__ float b2f(u16 u) {
  union { u32 i; float f; } v; v.i = ((u32)u) << 16; return v.f;
}
__device__ __forceinline__ u16 f2b(float f) {
  union { float f; u32 i; } v; v.f = f;
  u32 r = v.i + 0x7FFFu + ((v.i >> 16) & 1u);
  return (u16)(r >> 16);
}
__device__ __forceinline__ float rcpf(float x) { return __builtin_amdgcn_rcpf(x); }
__device__ __forceinline__ float sigf(float x) { return rcpf(1.0f + __expf(-x)); }
__device__ __forceinline__ float tanh_(float x) { return 1.0f - 2.0f * rcpf(__expf(2.0f * x) + 1.0f); }

__device__ __forceinline__ void gl_lds16(const u16* g, u16* l) {
  __builtin_amdgcn_global_load_lds(
      (const __attribute__((address_space(1))) u32*)g,
      (__attribute__((address_space(3))) u32*)l, 16, 0, 0);
}

// LDS-only barrier: waits own-wave DS ops, does NOT drain vmcnt (prefetch stays in flight)
__device__ __forceinline__ void bar_lds() {
  asm volatile("s_waitcnt lgkmcnt(0)" ::: "memory");
  __builtin_amdgcn_s_barrier();
}

// ---------------- weight conversion fp32 -> bf16 (optional gate-interleave row permute) --------
// perm=1 (Wih segs): logical row r (0..511) stored at prow = (r&127)*4 + (r>>7)
struct CvtArgs {
  const float* src[9];
  u16* dst[9];
  int n4[9];
  int perm[9];
};
__global__ __launch_bounds__(256) void k_cvt(CvtArgs a) {
  int seg = blockIdx.y;
  int i = blockIdx.x * 256 + threadIdx.x;
  if (i >= a.n4[seg]) return;
  float4 v = ((const float4*)a.src[seg])[i];
  ushort4 o;
  o.x = f2b(v.x); o.y = f2b(v.y); o.z = f2b(v.z); o.w = f2b(v.w);
  int idx = i;
  if (a.perm[seg]) {
    int r = i >> 6, c4 = i & 63;
    idx = (((r & 127) << 2) + (r >> 7)) * 64 + c4;
  }
  ((ushort4*)a.dst[seg])[idx] = o;
}

// ------- transpose input [B,C,H,W] -> A_h bf16 [(b,w,h)][c]; also channel means -------
__global__ __launch_bounds__(256) void k_tin(const float* __restrict__ in,
                                             u16* __restrict__ A,
                                             float* __restrict__ meansum) {
  int b = blockIdx.z, h = blockIdx.y, c0 = blockIdx.x * 64;
  int t = threadIdx.x, lane = t & 63, q = t >> 6;
  __shared__ u16 lT[64][66];
  const float* src = in + ((b * 256 + c0) * 64 + h) * 64;
#pragma unroll 4
  for (int i = 0; i < 16; ++i) {
    int cl = q * 16 + i;
    float v = src[cl * 4096 + lane];
    lT[cl][lane] = f2b(v);
    float s = v;
#pragma unroll
    for (int off = 32; off; off >>= 1) s += __shfl_xor(s, off);
    if (lane == 0) atomicAdd(&meansum[b * 256 + c0 + cl], s);
  }
  __syncthreads();
  u16* dst = A + (b * 4096 + h) * 256 + c0;
#pragma unroll 4
  for (int i = 0; i < 16; ++i) {
    int w = q * 16 + i;
    dst[w * 16384 + lane] = lT[lane][w];
  }
}

// ------- q_avg[b][o] = softmax_o( Wl[o,:] . mean_c ) -------
__global__ __launch_bounds__(256) void k_qavg(const float* __restrict__ meansum,
                                              const float* __restrict__ Wl,
                                              float* __restrict__ qavg) {
  int b = blockIdx.x, t = threadIdx.x;
  __shared__ float mean[256];
  __shared__ float red[256];
  mean[t] = meansum[b * 256 + t] * (1.0f / 4096.0f);
  __syncthreads();
  const float* wr = Wl + t * 256;
  float acc = 0.0f;
  for (int c = 0; c < 256; ++c) acc = fmaf(wr[c], mean[c], acc);
  red[t] = acc; __syncthreads();
  for (int s = 128; s; s >>= 1) { if (t < s) red[t] = fmaxf(red[t], red[t + s]); __syncthreads(); }
  float mx = red[0]; __syncthreads();
  float e = __expf(acc - mx);
  red[t] = e; __syncthreads();
  for (int s = 128; s; s >>= 1) { if (t < s) red[t] += red[t + s]; __syncthreads(); }
  qavg[b * 256 + t] = e / red[0];
}

// ------- 128x128-tile bf16 MFMA GEMM (m97 structure, gload_lds + XOR swizzle) -------
// W rows may be gate-interleave-permuted; bias indexed via inverse map.
__global__ __launch_bounds__(256, 4) void k_gemm2(const u16* __restrict__ A,
                                                  const u16* __restrict__ W,
                                                  const float* __restrict__ bias0,
                                                  const float* __restrict__ bias1,
                                                  u16* __restrict__ out, int nstride, int NT) {
  int nwg = gridDim.x;
  int q = nwg >> 3;
  int bid = blockIdx.x;
  int swz = (bid & 7) * q + (bid >> 3);
  int mt = swz / NT, nt = swz % NT;
  int mb = mt << 7, nb = nt << 7;
  int t = threadIdx.x, lane = t & 63, wid = t >> 6;
  int laneg = lane & 15, lk = lane >> 4;
  __shared__ __align__(16) u16 lA[128][64];
  __shared__ __align__(16) u16 lW[128][64];
  f4v acc[4][4] = {};
  int wm = wid >> 1, wn = wid & 1;
  for (int kb = 0; kb < 4; ++kb) {
    if (kb) __syncthreads();
#pragma unroll
    for (int k = 0; k < 4; ++k) {
      int rb = (wid << 5) + (k << 3);          // wave-uniform row base (8 rows/instr)
      int r = rb + (lane >> 3);                // this lane's row
      int cs = (lane & 7) ^ (r & 7);           // inverse-swizzled source chunk
      const u16* ga = A + (mb + r) * 256 + (kb << 6) + (cs << 3);
      const u16* gw = W + (nb + r) * 256 + (kb << 6) + (cs << 3);
      gl_lds16(ga, &lA[rb][0]);
      gl_lds16(gw, &lW[rb][0]);
    }
    __syncthreads();
#pragma unroll
    for (int kk = 0; kk < 2; ++kk) {
      s8v af[4], bf[4];
#pragma unroll
      for (int m = 0; m < 4; ++m) {
        int r = (wm << 6) + (m << 4) + laneg;
        int c = ((kk << 2) + lk) ^ (r & 7);
        af[m] = *(const s8v*)&lA[r][c << 3];
      }
#pragma unroll
      for (int n = 0; n < 4; ++n) {
        int r = (wn << 6) + (n << 4) + laneg;
        int c = ((kk << 2) + lk) ^ (r & 7);
        bf[n] = *(const s8v*)&lW[r][c << 3];
      }
#pragma unroll
      for (int m = 0; m < 4; ++m)
#pragma unroll
        for (int n = 0; n < 4; ++n)
          acc[m][n] = __builtin_amdgcn_mfma_f32_16x16x32_bf16(af[m], bf[n], acc[m][n], 0, 0, 0);
    }
  }
#pragma unroll
  for (int m = 0; m < 4; ++m) {
    int row0 = mb + (wm << 6) + (m << 4) + (lk << 2);
#pragma unroll
    for (int n = 0; n < 4; ++n) {
      int col = nb + (wn << 6) + (n << 4) + laneg;   // permuted index
      float bv = 0.0f;
      if (bias0) {
        int qd = col & 511;
        int l = (col & 512) + ((qd & 3) << 7) + (qd >> 2);   // logical gate-col
        bv = (l < 512) ? bias0[l] : bias1[l - 512];
      }
      int row0b = row0;
#pragma unroll
      for (int j = 0; j < 4; ++j)
        out[(row0b + j) * nstride + col] = f2b(acc[m][n][j] + bv);
    }
  }
}

// ------- bidirectional LSTM recurrence v3: gate-interleaved pre -> uint2 loads -------
// pre: bf16 [s*64+t][dir(2)][hcl(128)][g(4)]  (permuted cols)
// Whh2: bf16 [2][512][128] logical rows; outb: bf16 [(s/64)*4096 + t*64 + s%64][256]
__global__ __launch_bounds__(512) void k_recur(const u16* __restrict__ pre,
                                               const u16* __restrict__ Whh2,
                                               u16* __restrict__ outb) {
  int dir = blockIdx.y;
  int s0 = blockIdx.x << 4;                 // 16 sequences per block
  int t = threadIdx.x, lane = t & 63, w = t >> 6;  // 8 waves
  int laneg = lane & 15, lk = lane >> 4;
  const u16* Wd = Whh2 + dir * 65536;
  int hc = w << 4;                          // this wave's hidden-col base [hc, hc+16)
  s8v bfr[4][4];
#pragma unroll
  for (int g = 0; g < 4; ++g)
#pragma unroll
    for (int kk = 0; kk < 4; ++kk)
      bfr[g][kk] = *(const s8v*)(Wd + (g * 128 + hc + laneg) * 128 + kk * 32 + lk * 8);
  __shared__ __align__(16) u16 hb[2][16][136];
  for (int i = t; i < 2 * 16 * 136; i += 512) ((u16*)hb)[i] = 0;
  float cs[4] = {0.f, 0.f, 0.f, 0.f};
  int tc0 = dir ? 63 : 0;
  int dstep = dir ? -1 : 1;
  const u16* pbase = pre + (dir << 9) + ((hc + laneg) << 2);
  const u16* pA[4];
  const u16* pB[4];
#pragma unroll
  for (int j = 0; j < 4; ++j) {
    int sr = (s0 + lk * 4 + j) * 64;
    pA[j] = pbase + (sr + tc0) * 1024;
    pB[j] = pbase + (sr + tc0 + dstep) * 1024;
  }
  uint2 pfA[4], pfB[4];
#pragma unroll
  for (int j = 0; j < 4; ++j) {
    pfA[j] = *(const uint2*)pA[j];
    pfB[j] = *(const uint2*)pB[j];
  }
  u16* ob = outb + (((s0 >> 6) << 12) + (s0 & 63) + lk * 4 + tc0 * 64) * 256 + (dir << 7) + hc + laneg;
  long ostep = (long)(dstep * 64) * 256;
  int pstep = dstep * 2048;                 // two time-steps (elements)
  __syncthreads();
  int cur = 0;
  auto halfstep = [&](uint2 (&pf)[4], const u16* (&pb)[4], bool doLoad) {
    f4v acc[4];
#pragma unroll
    for (int j = 0; j < 4; ++j) {
      union { u32 u; float f; } a0, a1, a2, a3;
      a0.u = pf[j].x << 16;
      a1.u = pf[j].x & 0xffff0000u;
      a2.u = pf[j].y << 16;
      a3.u = pf[j].y & 0xffff0000u;
      acc[0][j] = a0.f; acc[1][j] = a1.f; acc[2][j] = a2.f; acc[3][j] = a3.f;
    }
    if (doLoad) {
#pragma unroll
      for (int j = 0; j < 4; ++j) {
        pb[j] += pstep;
        pf[j] = *(const uint2*)pb[j];
      }
    }
    s8v afr[4];
#pragma unroll
    for (int kk = 0; kk < 4; ++kk)
      afr[kk] = *(const s8v*)&hb[cur][laneg][kk * 32 + lk * 8];
#pragma unroll
    for (int g = 0; g < 4; ++g)
#pragma unroll
      for (int kk = 0; kk < 4; ++kk)
        acc[g] = __builtin_amdgcn_mfma_f32_16x16x32_bf16(afr[kk], bfr[g][kk], acc[g], 0, 0, 0);
    int nxt = cur ^ 1;
#pragma unroll
    for (int j = 0; j < 4; ++j) {
      float iv = sigf(acc[0][j]);
      float fv = sigf(acc[1][j]);
      float gv = tanh_(acc[2][j]);
      float ov = sigf(acc[3][j]);
      float c = fv * cs[j] + iv * gv;
      cs[j] = c;
      float hv = ov * tanh_(c);
      u16 hv16 = f2b(hv);
      hb[nxt][lk * 4 + j][hc + laneg] = hv16;
      ob[j * 256] = hv16;
    }
    ob += ostep;
    bar_lds();
    cur = nxt;
  };
  for (int st = 0; st < 64; st += 2) {
    halfstep(pfA, pA, st < 62);   // loads tc(st+2)
    halfstep(pfB, pB, st < 61);   // loads tc(st+3)
  }
}

// ------- stage 1: per-(b,chunk,o) max & sumexp over 256 rows -------
__global__ __launch_bounds__(256) void k_smr_p(const u16* __restrict__ VF,
                                               float* __restrict__ pm,
                                               float* __restrict__ pZ) {
  int ch = blockIdx.x, b = blockIdx.y;
  int o = threadIdx.x;
  const u16* p = VF + (b * 4096 + ch * 256) * 256 + o;
  float m0 = -1e30f, m1 = -1e30f, m2 = -1e30f, m3 = -1e30f;
  float s0 = 0.f, s1 = 0.f, s2 = 0.f, s3 = 0.f;
  for (int s = 0; s < 256; s += 4) {
    float x0 = b2f(p[(s + 0) * 256]);
    float x1 = b2f(p[(s + 1) * 256]);
    float x2 = b2f(p[(s + 2) * 256]);
    float x3 = b2f(p[(s + 3) * 256]);
    if (x0 > m0) { s0 = s0 * __expf(m0 - x0) + 1.f; m0 = x0; } else s0 += __expf(x0 - m0);
    if (x1 > m1) { s1 = s1 * __expf(m1 - x1) + 1.f; m1 = x1; } else s1 += __expf(x1 - m1);
    if (x2 > m2) { s2 = s2 * __expf(m2 - x2) + 1.f; m2 = x2; } else s2 += __expf(x2 - m2);
    if (x3 > m3) { s3 = s3 * __expf(m3 - x3) + 1.f; m3 = x3; } else s3 += __expf(x3 - m3);
  }
  float M = fmaxf(fmaxf(m0, m1), fmaxf(m2, m3));
  float S = s0 * __expf(m0 - M) + s1 * __expf(m1 - M) + s2 * __expf(m2 - M) + s3 * __expf(m3 - M);
  int idx = (b * 16 + ch) * 256 + o;
  pm[idx] = M; pZ[idx] = S;
}

// ------- stage 2: reduce 16 chunks -------
__global__ __launch_bounds__(256) void k_smr_f(const float* __restrict__ pm,
                                               const float* __restrict__ pZ,
                                               float* __restrict__ mbuf,
                                               float* __restrict__ Zbuf) {
  int b = blockIdx.x, o = threadIdx.x;
  float M = -1e30f;
#pragma unroll
  for (int c = 0; c < 16; ++c) M = fmaxf(M, pm[(b * 16 + c) * 256 + o]);
  float S = 0.f;
#pragma unroll
  for (int c = 0; c < 16; ++c) S += pZ[(b * 16 + c) * 256 + o] * __expf(pm[(b * 16 + c) * 256 + o] - M);
  mbuf[b * 256 + o] = M;
  Zbuf[b * 256 + o] = S;
}

// ------- attention logits: att[row] = sum_o (qavg[o]/Z[o]) * exp(VF[row][o]-m[o]) -------
__global__ __launch_bounds__(256) void k_att(const u16* __restrict__ VF,
                                             const float* __restrict__ qavg,
                                             const float* __restrict__ mbuf,
                                             const float* __restrict__ Zbuf,
                                             float* __restrict__ att) {
  int bx = blockIdx.x;
  int b = bx >> 6;
  int rowbase = bx * 64;
  int t = threadIdx.x, lane = t & 63, wid = t >> 6;
  __shared__ __align__(16) float lwo[256];
  __shared__ __align__(16) float lmo[256];
  {
    float Z = Zbuf[b * 256 + t];
    lwo[t] = qavg[b * 256 + t] / Z;
    lmo[t] = mbuf[b * 256 + t];
  }
  __syncthreads();
  float4 wo = *(const float4*)&lwo[lane * 4];
  float4 mo = *(const float4*)&lmo[lane * 4];
  for (int i = 0; i < 16; ++i) {
    int row = rowbase + wid * 16 + i;
    uint2 v = *(const uint2*)&VF[row * 256 + lane * 4];
    float x0 = b2f((u16)(v.x & 0xffff)), x1 = b2f((u16)(v.x >> 16));
    float x2 = b2f((u16)(v.y & 0xffff)), x3 = b2f((u16)(v.y >> 16));
    float p = wo.x * __expf(x0 - mo.x) + wo.y * __expf(x1 - mo.y) +
              wo.z * __expf(x2 - mo.z) + wo.w * __expf(x3 - mo.w);
#pragma unroll
    for (int off = 32; off; off >>= 1) p += __shfl_xor(p, off);
    if (lane == 0) att[row] = p;
  }
}

// ------- final: out = in * (1 + alpha * sigmoid(att)) -------
__global__ __launch_bounds__(256) void k_final(const float* __restrict__ in,
                                               const float* __restrict__ att,
                                               const float* __restrict__ alpha,
                                               float* __restrict__ out) {
  float al = alpha[0];
  int stride = gridDim.x * 256;
  for (int i = blockIdx.x * 256 + threadIdx.x; i < 4194304; i += stride) {
    float4 v = ((const float4*)in)[i];
    int flat = i * 4;
    int b = flat >> 20;
    int sp = flat & 4095;
    float4 a4 = *(const float4*)&att[b * 4096 + sp];
    float4 r;
    r.x = v.x * (1.f + al * sigf(a4.x));
    r.y = v.y * (1.f + al * sigf(a4.y));
    r.z = v.z * (1.f + al * sigf(a4.z));
    r.w = v.w * (1.f + al * sigf(a4.w));
    ((float4*)out)[i] = r;
  }
}

extern "C" void kernel_launch(void* const* d_in, const int* in_sizes, int n_in,
                              void* d_out, int out_size, void* d_ws, size_t ws_size,
                              hipStream_t stream) {
  const float* input   = (const float*)d_in[0];
  const float* h_Wih_f = (const float*)d_in[1];
  const float* h_Whh_f = (const float*)d_in[2];
  const float* h_b_f   = (const float*)d_in[3];
  const float* h_Wih_b = (const float*)d_in[4];
  const float* h_Whh_b = (const float*)d_in[5];
  const float* h_b_b   = (const float*)d_in[6];
  const float* v_Wih_f = (const float*)d_in[7];
  const float* v_Whh_f = (const float*)d_in[8];
  const float* v_b_f   = (const float*)d_in[9];
  const float* v_Wih_b = (const float*)d_in[10];
  const float* v_Whh_b = (const float*)d_in[11];
  const float* v_b_b   = (const float*)d_in[12];
  const float* Wr      = (const float*)d_in[13];
  const float* Wl      = (const float*)d_in[14];
  const float* alphap  = (const float*)d_in[15];

  char* ws = (char*)d_ws;
  u16* Ah     = (u16*)(ws + 0);            // 33,554,432 B  (also reused as A_r, then pm/pZ)
  u16* pre    = (u16*)(ws + 33554432);     // 134,217,728 B (also reused as VF)
  u16* Wh     = (u16*)(ws + 167772160);    // 524,288
  u16* Wv     = (u16*)(ws + 168296448);    // 524,288
  u16* WhhH   = (u16*)(ws + 168820736);    // 262,144
  u16* WhhV   = (u16*)(ws + 169082880);    // 262,144
  u16* Wrb    = (u16*)(ws + 169345024);    // 131,072
  float* meansum = (float*)(ws + 169476096); // 16,384
  float* qavg = (float*)(ws + 169492480);  // 16,384
  float* mbuf = (float*)(ws + 169508864);  // 16,384
  float* Zbuf = (float*)(ws + 169525248);  // 16,384
  float* attb = (float*)(ws + 169541632);  // 262,144
  u16* Av = (u16*)d_out;   // horizontal biLSTM output lives in d_out until the end
  u16* Ar = Ah;
  u16* VF = pre;
  float* pm = (float*)(ws + 0);            // 262,144 (Ah region, dead by then)
  float* pZ = (float*)(ws + 262144);       // 262,144

  (void)hipMemsetAsync(meansum, 0, 16 * 256 * 4, stream);

  CvtArgs ca;
  ca.src[0] = h_Wih_f; ca.dst[0] = Wh;          ca.n4[0] = 32768; ca.perm[0] = 1;
  ca.src[1] = h_Wih_b; ca.dst[1] = Wh + 131072; ca.n4[1] = 32768; ca.perm[1] = 1;
  ca.src[2] = v_Wih_f; ca.dst[2] = Wv;          ca.n4[2] = 32768; ca.perm[2] = 1;
  ca.src[3] = v_Wih_b; ca.dst[3] = Wv + 131072; ca.n4[3] = 32768; ca.perm[3] = 1;
  ca.src[4] = h_Whh_f; ca.dst[4] = WhhH;         ca.n4[4] = 16384; ca.perm[4] = 0;
  ca.src[5] = h_Whh_b; ca.dst[5] = WhhH + 65536; ca.n4[5] = 16384; ca.perm[5] = 0;
  ca.src[6] = v_Whh_f; ca.dst[6] = WhhV;         ca.n4[6] = 16384; ca.perm[6] = 0;
  ca.src[7] = v_Whh_b; ca.dst[7] = WhhV + 65536; ca.n4[7] = 16384; ca.perm[7] = 0;
  ca.src[8] = Wr;      ca.dst[8] = Wrb;          ca.n4[8] = 16384; ca.perm[8] = 0;
  k_cvt<<<dim3(128, 9), 256, 0, stream>>>(ca);

  k_tin<<<dim3(4, 64, 16), 256, 0, stream>>>(input, Ah, meansum);
  k_qavg<<<16, 256, 0, stream>>>(meansum, Wl, qavg);

  k_gemm2<<<4096, 256, 0, stream>>>(Ah, Wh, h_b_f, h_b_b, pre, 1024, 8);
  k_recur<<<dim3(64, 2), 512, 0, stream>>>(pre, WhhH, Av);
  k_gemm2<<<4096, 256, 0, stream>>>(Av, Wv, v_b_f, v_b_b, pre, 1024, 8);
  k_recur<<<dim3(64, 2), 512, 0, stream>>>(pre, WhhV, Ar);
  k_gemm2<<<1024, 256, 0, stream>>>(Ar, Wrb, nullptr, nullptr, VF, 256, 2);

  k_smr_p<<<dim3(16, 16), 256, 0, stream>>>(VF, pm, pZ);
  k_smr_f<<<16, 256, 0, stream>>>(pm, pZ, mbuf, Zbuf);
  k_att<<<1024, 256, 0, stream>>>(VF, qavg, mbuf, Zbuf, attb);
  k_final<<<2048, 256, 0, stream>>>(input, attb, alphap, (float*)d_out);
}

// Round 6
// 411.862 us; speedup vs baseline: 2.2509x; 1.0773x over previous
//
#include <hip/hip_runtime.h>
#include <hip/hip_bf16.h>

typedef unsigned short u16;
typedef unsigned int u32;
typedef __attribute__((ext_vector_type(8))) short s8v;   // 8 x bf16
typedef __attribute__((ext_vector_type(4))) float f4v;   // mfma acc

__device__ __forceinline__ float b2f(u16 u) {
  union { u32 i; float f; } v; v.i = ((u32)u) << 16; return v.f;
}
__device__ __forceinline__ u16 f2b(float f) {
  union { float f; u32 i; } v; v.f = f;
  u32 r = v.i + 0x7FFFu + ((v.i >> 16) & 1u);
  return (u16)(r >> 16);
}
__device__ __forceinline__ float rcpf(float x) { return __builtin_amdgcn_rcpf(x); }
__device__ __forceinline__ float ex2(float x) {
#if __has_builtin(__builtin_amdgcn_exp2f)
  return __builtin_amdgcn_exp2f(x);
#else
  return exp2f(x);
#endif
}
__device__ __forceinline__ float sigf(float x) { return rcpf(1.0f + __expf(-x)); }

#define GS_IFO 1.4426950408889634f
#define GS_G   2.8853900817779268f

__device__ __forceinline__ void gl_lds16(const u16* g, u16* l) {
  __builtin_amdgcn_global_load_lds(
      (const __attribute__((address_space(1))) u32*)g,
      (__attribute__((address_space(3))) u32*)l, 16, 0, 0);
}

// LDS-only barrier: waits own-wave DS ops, does NOT drain vmcnt
__device__ __forceinline__ void bar_lds() {
  asm volatile("s_waitcnt lgkmcnt(0)" ::: "memory");
  __builtin_amdgcn_s_barrier();
}

// ---------------- weight conversion fp32 -> bf16 ----------------
// perm: gate-interleave row permute (Wih). scl: multiply rows by gate scale (exp2 domain).
// sh: log2(float4s per row) for row recovery.
struct CvtArgs {
  const float* src[9];
  u16* dst[9];
  int n4[9];
  int perm[9];
  int scl[9];
  int sh[9];
};
__global__ __launch_bounds__(256) void k_cvt(CvtArgs a) {
  int seg = blockIdx.y;
  int i = blockIdx.x * 256 + threadIdx.x;
  if (i >= a.n4[seg]) return;
  float4 v = ((const float4*)a.src[seg])[i];
  if (a.scl[seg]) {
    int r = i >> a.sh[seg];
    float s = (((r >> 7) & 3) == 2) ? GS_G : GS_IFO;
    v.x *= s; v.y *= s; v.z *= s; v.w *= s;
  }
  ushort4 o;
  o.x = f2b(v.x); o.y = f2b(v.y); o.z = f2b(v.z); o.w = f2b(v.w);
  int idx = i;
  if (a.perm[seg]) {
    int r = i >> 6, c4 = i & 63;
    idx = (((r & 127) << 2) + (r >> 7)) * 64 + c4;
  }
  ((ushort4*)a.dst[seg])[idx] = o;
}

// ------- transpose input [B,C,H,W] -> A_h bf16 [(b,w,h)][c]; also channel means -------
__global__ __launch_bounds__(256) void k_tin(const float* __restrict__ in,
                                             u16* __restrict__ A,
                                             float* __restrict__ meansum) {
  int b = blockIdx.z, h = blockIdx.y, c0 = blockIdx.x * 64;
  int t = threadIdx.x, lane = t & 63, q = t >> 6;
  __shared__ u16 lT[64][66];
  const float* src = in + ((b * 256 + c0) * 64 + h) * 64;
#pragma unroll 4
  for (int i = 0; i < 16; ++i) {
    int cl = q * 16 + i;
    float v = src[cl * 4096 + lane];
    lT[cl][lane] = f2b(v);
    float s = v;
#pragma unroll
    for (int off = 32; off; off >>= 1) s += __shfl_xor(s, off);
    if (lane == 0) atomicAdd(&meansum[b * 256 + c0 + cl], s);
  }
  __syncthreads();
  u16* dst = A + (b * 4096 + h) * 256 + c0;
#pragma unroll 4
  for (int i = 0; i < 16; ++i) {
    int w = q * 16 + i;
    dst[w * 16384 + lane] = lT[lane][w];
  }
}

// ------- q_avg[b][o] = softmax_o( Wl[o,:] . mean_c ) -------
__global__ __launch_bounds__(256) void k_qavg(const float* __restrict__ meansum,
                                              const float* __restrict__ Wl,
                                              float* __restrict__ qavg) {
  int b = blockIdx.x, t = threadIdx.x;
  __shared__ float mean[256];
  __shared__ float red[256];
  mean[t] = meansum[b * 256 + t] * (1.0f / 4096.0f);
  __syncthreads();
  const float* wr = Wl + t * 256;
  float acc = 0.0f;
  for (int c = 0; c < 256; ++c) acc = fmaf(wr[c], mean[c], acc);
  red[t] = acc; __syncthreads();
  for (int s = 128; s; s >>= 1) { if (t < s) red[t] = fmaxf(red[t], red[t + s]); __syncthreads(); }
  float mx = red[0]; __syncthreads();
  float e = __expf(acc - mx);
  red[t] = e; __syncthreads();
  for (int s = 128; s; s >>= 1) { if (t < s) red[t] += red[t + s]; __syncthreads(); }
  qavg[b * 256 + t] = e / red[0];
}

// ------- 128x128-tile bf16 MFMA GEMM (m97 structure) -------
__global__ __launch_bounds__(256, 4) void k_gemm2(const u16* __restrict__ A,
                                                  const u16* __restrict__ W,
                                                  const float* __restrict__ bias0,
                                                  const float* __restrict__ bias1,
                                                  u16* __restrict__ out, int nstride, int NT) {
  int nwg = gridDim.x;
  int q = nwg >> 3;
  int bid = blockIdx.x;
  int swz = (bid & 7) * q + (bid >> 3);
  int mt = swz / NT, nt = swz % NT;
  int mb = mt << 7, nb = nt << 7;
  int t = threadIdx.x, lane = t & 63, wid = t >> 6;
  int laneg = lane & 15, lk = lane >> 4;
  __shared__ __align__(16) u16 lA[128][64];
  __shared__ __align__(16) u16 lW[128][64];
  f4v acc[4][4] = {};
  int wm = wid >> 1, wn = wid & 1;
  for (int kb = 0; kb < 4; ++kb) {
    if (kb) __syncthreads();
#pragma unroll
    for (int k = 0; k < 4; ++k) {
      int rb = (wid << 5) + (k << 3);
      int r = rb + (lane >> 3);
      int cs = (lane & 7) ^ (r & 7);
      const u16* ga = A + (mb + r) * 256 + (kb << 6) + (cs << 3);
      const u16* gw = W + (nb + r) * 256 + (kb << 6) + (cs << 3);
      gl_lds16(ga, &lA[rb][0]);
      gl_lds16(gw, &lW[rb][0]);
    }
    __syncthreads();
#pragma unroll
    for (int kk = 0; kk < 2; ++kk) {
      s8v af[4], bf[4];
#pragma unroll
      for (int m = 0; m < 4; ++m) {
        int r = (wm << 6) + (m << 4) + laneg;
        int c = ((kk << 2) + lk) ^ (r & 7);
        af[m] = *(const s8v*)&lA[r][c << 3];
      }
#pragma unroll
      for (int n = 0; n < 4; ++n) {
        int r = (wn << 6) + (n << 4) + laneg;
        int c = ((kk << 2) + lk) ^ (r & 7);
        bf[n] = *(const s8v*)&lW[r][c << 3];
      }
#pragma unroll
      for (int m = 0; m < 4; ++m)
#pragma unroll
        for (int n = 0; n < 4; ++n)
          acc[m][n] = __builtin_amdgcn_mfma_f32_16x16x32_bf16(af[m], bf[n], acc[m][n], 0, 0, 0);
    }
  }
#pragma unroll
  for (int m = 0; m < 4; ++m) {
    int row0 = mb + (wm << 6) + (m << 4) + (lk << 2);
#pragma unroll
    for (int n = 0; n < 4; ++n) {
      int col = nb + (wn << 6) + (n << 4) + laneg;   // permuted index
      float bv = 0.0f;
      if (bias0) {
        int qd = col & 511;
        int l = (col & 512) + ((qd & 3) << 7) + (qd >> 2);   // logical gate-col
        float gs = (((l >> 7) & 3) == 2) ? GS_G : GS_IFO;
        bv = ((l < 512) ? bias0[l] : bias1[l - 512]) * gs;
      }
#pragma unroll
      for (int j = 0; j < 4; ++j)
        out[(row0 + j) * nstride + col] = f2b(acc[m][n][j] + bv);
    }
  }
}

// ------- bidirectional LSTM recurrence v4: exp2-domain gates, LDS-staged coalesced stores -------
// pre: bf16 [s*64+t][dir(2)][hcl(128)][g(4)] (permuted, gate-scaled cols)
// Whh2: bf16 [2][512][128] (gate-scaled rows); outb: bf16 [(s/64)*4096 + t*64 + s%64][256]
__global__ __launch_bounds__(512) void k_recur(const u16* __restrict__ pre,
                                               const u16* __restrict__ Whh2,
                                               u16* __restrict__ outb) {
  int dir = blockIdx.y;
  int s0 = blockIdx.x << 4;                 // 16 sequences per block
  int t = threadIdx.x, lane = t & 63, w = t >> 6;  // 8 waves
  int laneg = lane & 15, lk = lane >> 4;
  const u16* Wd = Whh2 + dir * 65536;
  int hc = w << 4;
  s8v bfr[4][4];
#pragma unroll
  for (int g = 0; g < 4; ++g)
#pragma unroll
    for (int kk = 0; kk < 4; ++kk)
      bfr[g][kk] = *(const s8v*)(Wd + (g * 128 + hc + laneg) * 128 + kk * 32 + lk * 8);
  __shared__ __align__(16) u16 hb[2][16][136];
  for (int i = t; i < 2 * 16 * 136; i += 512) ((u16*)hb)[i] = 0;
  float cs[4] = {0.f, 0.f, 0.f, 0.f};
  int tc0 = dir ? 63 : 0;
  int dstep = dir ? -1 : 1;
  const u16* pbase = pre + (dir << 9) + ((hc + laneg) << 2);
  const u16* pA[4];
  const u16* pB[4];
#pragma unroll
  for (int j = 0; j < 4; ++j) {
    int sr = (s0 + lk * 4 + j) * 64;
    pA[j] = pbase + (sr + tc0) * 1024;
    pB[j] = pbase + (sr + tc0 + dstep) * 1024;
  }
  uint2 pfA[4], pfB[4];
#pragma unroll
  for (int j = 0; j < 4; ++j) {
    pfA[j] = *(const uint2*)pA[j];
    pfB[j] = *(const uint2*)pB[j];
  }
  int rowb = ((s0 >> 6) << 12) + (s0 & 63);
  u16* obase = outb + (dir << 7);
  int pstep = dstep * 2048;
  __syncthreads();
  int cur = 0;
  // store hb[cur] (h of time tct) as coalesced rows; safe: writes this step go to hb[cur^1]
  auto store_h = [&](int tct) {
    if (w < 4) {
      int r = (w << 2) + (lane >> 4);
      uint4 v = ((const uint4*)&hb[cur][r][0])[lane & 15];
      *(uint4*)(obase + (rowb + tct * 64 + r) * 256 + ((lane & 15) << 3)) = v;
    }
  };
  auto halfstep = [&](uint2 (&pf)[4], const u16* (&pb)[4], bool doLoad, int tc, bool doStore) {
    if (doStore) store_h(tc - dstep);
    f4v acc[4];
#pragma unroll
    for (int j = 0; j < 4; ++j) {
      union { u32 u; float f; } a0, a1, a2, a3;
      a0.u = pf[j].x << 16;
      a1.u = pf[j].x & 0xffff0000u;
      a2.u = pf[j].y << 16;
      a3.u = pf[j].y & 0xffff0000u;
      acc[0][j] = a0.f; acc[1][j] = a1.f; acc[2][j] = a2.f; acc[3][j] = a3.f;
    }
    if (doLoad) {
#pragma unroll
      for (int j = 0; j < 4; ++j) {
        pb[j] += pstep;
        pf[j] = *(const uint2*)pb[j];
      }
    }
    s8v afr[4];
#pragma unroll
    for (int kk = 0; kk < 4; ++kk)
      afr[kk] = *(const s8v*)&hb[cur][laneg][kk * 32 + lk * 8];
#pragma unroll
    for (int g = 0; g < 4; ++g)
#pragma unroll
      for (int kk = 0; kk < 4; ++kk)
        acc[g] = __builtin_amdgcn_mfma_f32_16x16x32_bf16(afr[kk], bfr[g][kk], acc[g], 0, 0, 0);
    int nxt = cur ^ 1;
#pragma unroll
    for (int j = 0; j < 4; ++j) {
      float iv = rcpf(1.0f + ex2(-acc[0][j]));
      float fv = rcpf(1.0f + ex2(-acc[1][j]));
      float gv = 1.0f - 2.0f * rcpf(1.0f + ex2(acc[2][j]));
      float ov = rcpf(1.0f + ex2(-acc[3][j]));
      float c = fv * cs[j] + iv * gv;
      cs[j] = c;
      float th = 1.0f - 2.0f * rcpf(1.0f + ex2(c * GS_G));
      float hv = ov * th;
      hb[nxt][lk * 4 + j][hc + laneg] = f2b(hv);
    }
    bar_lds();
    cur = nxt;
  };
  for (int st = 0; st < 64; st += 2) {
    halfstep(pfA, pA, st < 62, tc0 + st * dstep, st > 0);
    halfstep(pfB, pB, st < 61, tc0 + (st + 1) * dstep, true);
  }
  store_h(tc0 + 63 * dstep);
}

// ------- per-(b,chunk,o) sumexp over 256 rows (logits bounded, no max needed) -------
__global__ __launch_bounds__(256) void k_smr_p(const u16* __restrict__ VF,
                                               float* __restrict__ pZ) {
  int ch = blockIdx.x, b = blockIdx.y;
  int o = threadIdx.x;
  const u16* p = VF + (b * 4096 + ch * 256) * 256 + o;
  float s0 = 0.f, s1 = 0.f, s2 = 0.f, s3 = 0.f;
  for (int s = 0; s < 256; s += 4) {
    s0 += __expf(b2f(p[(s + 0) * 256]));
    s1 += __expf(b2f(p[(s + 1) * 256]));
    s2 += __expf(b2f(p[(s + 2) * 256]));
    s3 += __expf(b2f(p[(s + 3) * 256]));
  }
  pZ[(b * 16 + ch) * 256 + o] = (s0 + s1) + (s2 + s3);
}

// ------- attention logits: att[row] = sum_o (qavg[o]/Z[o]) * exp(VF[row][o]) -------
__global__ __launch_bounds__(256) void k_att(const u16* __restrict__ VF,
                                             const float* __restrict__ qavg,
                                             const float* __restrict__ pZ,
                                             float* __restrict__ att) {
  int bx = blockIdx.x;
  int b = bx >> 6;
  int rowbase = bx * 64;
  int t = threadIdx.x, lane = t & 63, wid = t >> 6;
  __shared__ __align__(16) float lwo[256];
  {
    float Z = 0.f;
#pragma unroll
    for (int c = 0; c < 16; ++c) Z += pZ[(b * 16 + c) * 256 + t];
    lwo[t] = qavg[b * 256 + t] / Z;
  }
  __syncthreads();
  float4 wo = *(const float4*)&lwo[lane * 4];
  for (int i = 0; i < 16; ++i) {
    int row = rowbase + wid * 16 + i;
    uint2 v = *(const uint2*)&VF[row * 256 + lane * 4];
    float x0 = b2f((u16)(v.x & 0xffff)), x1 = b2f((u16)(v.x >> 16));
    float x2 = b2f((u16)(v.y & 0xffff)), x3 = b2f((u16)(v.y >> 16));
    float p = wo.x * __expf(x0) + wo.y * __expf(x1) +
              wo.z * __expf(x2) + wo.w * __expf(x3);
#pragma unroll
    for (int off = 32; off; off >>= 1) p += __shfl_xor(p, off);
    if (lane == 0) att[row] = p;
  }
}

// ------- final: out = in * (1 + alpha * sigmoid(att)) -------
__global__ __launch_bounds__(256) void k_final(const float* __restrict__ in,
                                               const float* __restrict__ att,
                                               const float* __restrict__ alpha,
                                               float* __restrict__ out) {
  float al = alpha[0];
  int stride = gridDim.x * 256;
  for (int i = blockIdx.x * 256 + threadIdx.x; i < 4194304; i += stride) {
    float4 v = ((const float4*)in)[i];
    int flat = i * 4;
    int b = flat >> 20;
    int sp = flat & 4095;
    float4 a4 = *(const float4*)&att[b * 4096 + sp];
    float4 r;
    r.x = v.x * (1.f + al * sigf(a4.x));
    r.y = v.y * (1.f + al * sigf(a4.y));
    r.z = v.z * (1.f + al * sigf(a4.z));
    r.w = v.w * (1.f + al * sigf(a4.w));
    ((float4*)out)[i] = r;
  }
}

extern "C" void kernel_launch(void* const* d_in, const int* in_sizes, int n_in,
                              void* d_out, int out_size, void* d_ws, size_t ws_size,
                              hipStream_t stream) {
  const float* input   = (const float*)d_in[0];
  const float* h_Wih_f = (const float*)d_in[1];
  const float* h_Whh_f = (const float*)d_in[2];
  const float* h_b_f   = (const float*)d_in[3];
  const float* h_Wih_b = (const float*)d_in[4];
  const float* h_Whh_b = (const float*)d_in[5];
  const float* h_b_b   = (const float*)d_in[6];
  const float* v_Wih_f = (const float*)d_in[7];
  const float* v_Whh_f = (const float*)d_in[8];
  const float* v_b_f   = (const float*)d_in[9];
  const float* v_Wih_b = (const float*)d_in[10];
  const float* v_Whh_b = (const float*)d_in[11];
  const float* v_b_b   = (const float*)d_in[12];
  const float* Wr      = (const float*)d_in[13];
  const float* Wl      = (const float*)d_in[14];
  const float* alphap  = (const float*)d_in[15];

  char* ws = (char*)d_ws;
  u16* Ah     = (u16*)(ws + 0);            // 33,554,432 B (also A_r, then pZ)
  u16* pre    = (u16*)(ws + 33554432);     // 134,217,728 B (also VF)
  u16* Wh     = (u16*)(ws + 167772160);
  u16* Wv     = (u16*)(ws + 168296448);
  u16* WhhH   = (u16*)(ws + 168820736);
  u16* WhhV   = (u16*)(ws + 169082880);
  u16* Wrb    = (u16*)(ws + 169345024);
  float* meansum = (float*)(ws + 169476096);
  float* qavg = (float*)(ws + 169492480);
  float* attb = (float*)(ws + 169541632);
  u16* Av = (u16*)d_out;
  u16* Ar = Ah;
  u16* VF = pre;
  float* pZ = (float*)(ws + 0);            // 262,144 (Ah region, dead by then)

  (void)hipMemsetAsync(meansum, 0, 16 * 256 * 4, stream);

  CvtArgs ca;
  ca.src[0] = h_Wih_f; ca.dst[0] = Wh;          ca.n4[0] = 32768; ca.perm[0] = 1; ca.scl[0] = 1; ca.sh[0] = 6;
  ca.src[1] = h_Wih_b; ca.dst[1] = Wh + 131072; ca.n4[1] = 32768; ca.perm[1] = 1; ca.scl[1] = 1; ca.sh[1] = 6;
  ca.src[2] = v_Wih_f; ca.dst[2] = Wv;          ca.n4[2] = 32768; ca.perm[2] = 1; ca.scl[2] = 1; ca.sh[2] = 6;
  ca.src[3] = v_Wih_b; ca.dst[3] = Wv + 131072; ca.n4[3] = 32768; ca.perm[3] = 1; ca.scl[3] = 1; ca.sh[3] = 6;
  ca.src[4] = h_Whh_f; ca.dst[4] = WhhH;         ca.n4[4] = 16384; ca.perm[4] = 0; ca.scl[4] = 1; ca.sh[4] = 5;
  ca.src[5] = h_Whh_b; ca.dst[5] = WhhH + 65536; ca.n4[5] = 16384; ca.perm[5] = 0; ca.scl[5] = 1; ca.sh[5] = 5;
  ca.src[6] = v_Whh_f; ca.dst[6] = WhhV;         ca.n4[6] = 16384; ca.perm[6] = 0; ca.scl[6] = 1; ca.sh[6] = 5;
  ca.src[7] = v_Whh_b; ca.dst[7] = WhhV + 65536; ca.n4[7] = 16384; ca.perm[7] = 0; ca.scl[7] = 1; ca.sh[7] = 5;
  ca.src[8] = Wr;      ca.dst[8] = Wrb;          ca.n4[8] = 16384; ca.perm[8] = 0; ca.scl[8] = 0; ca.sh[8] = 5;
  k_cvt<<<dim3(128, 9), 256, 0, stream>>>(ca);

  k_tin<<<dim3(4, 64, 16), 256, 0, stream>>>(input, Ah, meansum);
  k_qavg<<<16, 256, 0, stream>>>(meansum, Wl, qavg);

  k_gemm2<<<4096, 256, 0, stream>>>(Ah, Wh, h_b_f, h_b_b, pre, 1024, 8);
  k_recur<<<dim3(64, 2), 512, 0, stream>>>(pre, WhhH, Av);
  k_gemm2<<<4096, 256, 0, stream>>>(Av, Wv, v_b_f, v_b_b, pre, 1024, 8);
  k_recur<<<dim3(64, 2), 512, 0, stream>>>(pre, WhhV, Ar);
  k_gemm2<<<1024, 256, 0, stream>>>(Ar, Wrb, nullptr, nullptr, VF, 256, 2);

  k_smr_p<<<dim3(16, 16), 256, 0, stream>>>(VF, pZ);
  k_att<<<1024, 256, 0, stream>>>(VF, qavg, pZ, attb);
  k_final<<<2048, 256, 0, stream>>>(input, attb, alphap, (float*)d_out);
}

// Round 7
// 391.344 us; speedup vs baseline: 2.3689x; 1.0524x over previous
//
#include <hip/hip_runtime.h>
#include <hip/hip_bf16.h>

typedef unsigned short u16;
typedef unsigned int u32;
typedef __attribute__((ext_vector_type(8))) short s8v;   // 8 x bf16
typedef __attribute__((ext_vector_type(4))) float f4v;   // mfma acc

__device__ __forceinline__ float b2f(u16 u) {
  union { u32 i; float f; } v; v.i = ((u32)u) << 16; return v.f;
}
__device__ __forceinline__ u16 f2b(float f) {
  union { float f; u32 i; } v; v.f = f;
  u32 r = v.i + 0x7FFFu + ((v.i >> 16) & 1u);
  return (u16)(r >> 16);
}
__device__ __forceinline__ float rcpf(float x) { return __builtin_amdgcn_rcpf(x); }
__device__ __forceinline__ float ex2(float x) {
#if __has_builtin(__builtin_amdgcn_exp2f)
  return __builtin_amdgcn_exp2f(x);
#else
  return exp2f(x);
#endif
}
__device__ __forceinline__ float sigf(float x) { return rcpf(1.0f + __expf(-x)); }

#define GS_IFO 1.4426950408889634f
#define GS_G   2.8853900817779268f

__device__ __forceinline__ void gl_lds16(const u16* g, u16* l) {
  __builtin_amdgcn_global_load_lds(
      (const __attribute__((address_space(1))) u32*)g,
      (__attribute__((address_space(3))) u32*)l, 16, 0, 0);
}

// LDS-only barrier: waits own-wave DS ops, does NOT drain vmcnt
__device__ __forceinline__ void bar_lds() {
  asm volatile("s_waitcnt lgkmcnt(0)" ::: "memory");
  __builtin_amdgcn_s_barrier();
}

// ---------------- weight conversion fp32 -> bf16 ----------------
// perm: gate-interleave row permute (Wih). scl: 0 none, 1 gate-pattern scale, 2 uniform log2e.
// sh: log2(float4s per row).
struct CvtArgs {
  const float* src[9];
  u16* dst[9];
  int n4[9];
  int perm[9];
  int scl[9];
  int sh[9];
};
__global__ __launch_bounds__(256) void k_cvt(CvtArgs a) {
  int seg = blockIdx.y;
  int i = blockIdx.x * 256 + threadIdx.x;
  if (i >= a.n4[seg]) return;
  float4 v = ((const float4*)a.src[seg])[i];
  if (a.scl[seg]) {
    float s;
    if (a.scl[seg] == 2) {
      s = GS_IFO;
    } else {
      int r = i >> a.sh[seg];
      s = (((r >> 7) & 3) == 2) ? GS_G : GS_IFO;
    }
    v.x *= s; v.y *= s; v.z *= s; v.w *= s;
  }
  ushort4 o;
  o.x = f2b(v.x); o.y = f2b(v.y); o.z = f2b(v.z); o.w = f2b(v.w);
  int idx = i;
  if (a.perm[seg]) {
    int r = i >> 6, c4 = i & 63;
    idx = (((r & 127) << 2) + (r >> 7)) * 64 + c4;
  }
  ((ushort4*)a.dst[seg])[idx] = o;
}

// ------- transpose input [B,C,H,W] -> A_h bf16 [(b,w,h)][c]; also channel means -------
__global__ __launch_bounds__(256) void k_tin(const float* __restrict__ in,
                                             u16* __restrict__ A,
                                             float* __restrict__ meansum) {
  int b = blockIdx.z, h = blockIdx.y, c0 = blockIdx.x * 64;
  int t = threadIdx.x, lane = t & 63, q = t >> 6;
  __shared__ u16 lT[64][66];
  const float* src = in + ((b * 256 + c0) * 64 + h) * 64;
#pragma unroll 4
  for (int i = 0; i < 16; ++i) {
    int cl = q * 16 + i;
    float v = src[cl * 4096 + lane];
    lT[cl][lane] = f2b(v);
    float s = v;
#pragma unroll
    for (int off = 32; off; off >>= 1) s += __shfl_xor(s, off);
    if (lane == 0) atomicAdd(&meansum[b * 256 + c0 + cl], s);
  }
  __syncthreads();
  u16* dst = A + (b * 4096 + h) * 256 + c0;
#pragma unroll 4
  for (int i = 0; i < 16; ++i) {
    int w = q * 16 + i;
    dst[w * 16384 + lane] = lT[lane][w];
  }
}

// ------- q_avg[b][o] = softmax_o( Wl[o,:] . mean_c ) -------
__global__ __launch_bounds__(256) void k_qavg(const float* __restrict__ meansum,
                                              const float* __restrict__ Wl,
                                              float* __restrict__ qavg) {
  int b = blockIdx.x, t = threadIdx.x;
  __shared__ float mean[256];
  __shared__ float red[256];
  mean[t] = meansum[b * 256 + t] * (1.0f / 4096.0f);
  __syncthreads();
  const float* wr = Wl + t * 256;
  float acc = 0.0f;
  for (int c = 0; c < 256; ++c) acc = fmaf(wr[c], mean[c], acc);
  red[t] = acc; __syncthreads();
  for (int s = 128; s; s >>= 1) { if (t < s) red[t] = fmaxf(red[t], red[t + s]); __syncthreads(); }
  float mx = red[0]; __syncthreads();
  float e = __expf(acc - mx);
  red[t] = e; __syncthreads();
  for (int s = 128; s; s >>= 1) { if (t < s) red[t] += red[t + s]; __syncthreads(); }
  qavg[b * 256 + t] = e / red[0];
}

// ------- 128x128-tile bf16 MFMA GEMM (m97 structure) -------
// Zsum != nullptr: store exp2(acc) as bf16 and atomically accumulate per-column sums.
__global__ __launch_bounds__(256, 4) void k_gemm2(const u16* __restrict__ A,
                                                  const u16* __restrict__ W,
                                                  const float* __restrict__ bias0,
                                                  const float* __restrict__ bias1,
                                                  u16* __restrict__ out, int nstride, int NT,
                                                  float* __restrict__ Zsum) {
  int nwg = gridDim.x;
  int q = nwg >> 3;
  int bid = blockIdx.x;
  int swz = (bid & 7) * q + (bid >> 3);
  int mt = swz / NT, nt = swz % NT;
  int mb = mt << 7, nb = nt << 7;
  int t = threadIdx.x, lane = t & 63, wid = t >> 6;
  int laneg = lane & 15, lk = lane >> 4;
  __shared__ __align__(16) u16 lA[128][64];
  __shared__ __align__(16) u16 lW[128][64];
  f4v acc[4][4] = {};
  int wm = wid >> 1, wn = wid & 1;
  for (int kb = 0; kb < 4; ++kb) {
    if (kb) __syncthreads();
#pragma unroll
    for (int k = 0; k < 4; ++k) {
      int rb = (wid << 5) + (k << 3);
      int r = rb + (lane >> 3);
      int cs = (lane & 7) ^ (r & 7);
      const u16* ga = A + (mb + r) * 256 + (kb << 6) + (cs << 3);
      const u16* gw = W + (nb + r) * 256 + (kb << 6) + (cs << 3);
      gl_lds16(ga, &lA[rb][0]);
      gl_lds16(gw, &lW[rb][0]);
    }
    __syncthreads();
#pragma unroll
    for (int kk = 0; kk < 2; ++kk) {
      s8v af[4], bf[4];
#pragma unroll
      for (int m = 0; m < 4; ++m) {
        int r = (wm << 6) + (m << 4) + laneg;
        int c = ((kk << 2) + lk) ^ (r & 7);
        af[m] = *(const s8v*)&lA[r][c << 3];
      }
#pragma unroll
      for (int n = 0; n < 4; ++n) {
        int r = (wn << 6) + (n << 4) + laneg;
        int c = ((kk << 2) + lk) ^ (r & 7);
        bf[n] = *(const s8v*)&lW[r][c << 3];
      }
#pragma unroll
      for (int m = 0; m < 4; ++m)
#pragma unroll
        for (int n = 0; n < 4; ++n)
          acc[m][n] = __builtin_amdgcn_mfma_f32_16x16x32_bf16(af[m], bf[n], acc[m][n], 0, 0, 0);
    }
  }
  if (Zsum) {
#pragma unroll
    for (int n = 0; n < 4; ++n) {
      int col = nb + (wn << 6) + (n << 4) + laneg;
      float csum = 0.f;
#pragma unroll
      for (int m = 0; m < 4; ++m) {
        int row0 = mb + (wm << 6) + (m << 4) + (lk << 2);
#pragma unroll
        for (int j = 0; j < 4; ++j) {
          float e = ex2(acc[m][n][j]);
          csum += e;
          out[(row0 + j) * nstride + col] = f2b(e);
        }
      }
      csum += __shfl_xor(csum, 16);
      csum += __shfl_xor(csum, 32);
      if (lk == 0) atomicAdd(&Zsum[((mb >> 12) << 8) + col], csum);
    }
  } else {
#pragma unroll
    for (int m = 0; m < 4; ++m) {
      int row0 = mb + (wm << 6) + (m << 4) + (lk << 2);
#pragma unroll
      for (int n = 0; n < 4; ++n) {
        int col = nb + (wn << 6) + (n << 4) + laneg;   // permuted index
        int qd = col & 511;
        int l = (col & 512) + ((qd & 3) << 7) + (qd >> 2);   // logical gate-col
        float gs = (((l >> 7) & 3) == 2) ? GS_G : GS_IFO;
        float bv = ((l < 512) ? bias0[l] : bias1[l - 512]) * gs;
#pragma unroll
        for (int j = 0; j < 4; ++j)
          out[(row0 + j) * nstride + col] = f2b(acc[m][n][j] + bv);
      }
    }
  }
}

// ------- bidirectional LSTM recurrence (exp2 gates, LDS-staged coalesced stores) -------
__global__ __launch_bounds__(512) void k_recur(const u16* __restrict__ pre,
                                               const u16* __restrict__ Whh2,
                                               u16* __restrict__ outb) {
  int dir = blockIdx.y;
  int s0 = blockIdx.x << 4;                 // 16 sequences per block
  int t = threadIdx.x, lane = t & 63, w = t >> 6;  // 8 waves
  int laneg = lane & 15, lk = lane >> 4;
  const u16* Wd = Whh2 + dir * 65536;
  int hc = w << 4;
  s8v bfr[4][4];
#pragma unroll
  for (int g = 0; g < 4; ++g)
#pragma unroll
    for (int kk = 0; kk < 4; ++kk)
      bfr[g][kk] = *(const s8v*)(Wd + (g * 128 + hc + laneg) * 128 + kk * 32 + lk * 8);
  __shared__ __align__(16) u16 hb[2][16][136];
  for (int i = t; i < 2 * 16 * 136; i += 512) ((u16*)hb)[i] = 0;
  float cs[4] = {0.f, 0.f, 0.f, 0.f};
  int tc0 = dir ? 63 : 0;
  int dstep = dir ? -1 : 1;
  const u16* pbase = pre + (dir << 9) + ((hc + laneg) << 2);
  const u16* pA[4];
  const u16* pB[4];
#pragma unroll
  for (int j = 0; j < 4; ++j) {
    int sr = (s0 + lk * 4 + j) * 64;
    pA[j] = pbase + (sr + tc0) * 1024;
    pB[j] = pbase + (sr + tc0 + dstep) * 1024;
  }
  uint2 pfA[4], pfB[4];
#pragma unroll
  for (int j = 0; j < 4; ++j) {
    pfA[j] = *(const uint2*)pA[j];
    pfB[j] = *(const uint2*)pB[j];
  }
  int rowb = ((s0 >> 6) << 12) + (s0 & 63);
  u16* obase = outb + (dir << 7);
  int pstep = dstep * 2048;
  __syncthreads();
  int cur = 0;
  auto store_h = [&](int tct) {
    if (w < 4) {
      int r = (w << 2) + (lane >> 4);
      uint4 v = ((const uint4*)&hb[cur][r][0])[lane & 15];
      *(uint4*)(obase + (rowb + tct * 64 + r) * 256 + ((lane & 15) << 3)) = v;
    }
  };
  auto halfstep = [&](uint2 (&pf)[4], const u16* (&pb)[4], bool doLoad, int tc, bool doStore) {
    if (doStore) store_h(tc - dstep);
    f4v acc[4];
#pragma unroll
    for (int j = 0; j < 4; ++j) {
      union { u32 u; float f; } a0, a1, a2, a3;
      a0.u = pf[j].x << 16;
      a1.u = pf[j].x & 0xffff0000u;
      a2.u = pf[j].y << 16;
      a3.u = pf[j].y & 0xffff0000u;
      acc[0][j] = a0.f; acc[1][j] = a1.f; acc[2][j] = a2.f; acc[3][j] = a3.f;
    }
    if (doLoad) {
#pragma unroll
      for (int j = 0; j < 4; ++j) {
        pb[j] += pstep;
        pf[j] = *(const uint2*)pb[j];
      }
    }
    s8v afr[4];
#pragma unroll
    for (int kk = 0; kk < 4; ++kk)
      afr[kk] = *(const s8v*)&hb[cur][laneg][kk * 32 + lk * 8];
#pragma unroll
    for (int g = 0; g < 4; ++g)
#pragma unroll
      for (int kk = 0; kk < 4; ++kk)
        acc[g] = __builtin_amdgcn_mfma_f32_16x16x32_bf16(afr[kk], bfr[g][kk], acc[g], 0, 0, 0);
    int nxt = cur ^ 1;
#pragma unroll
    for (int j = 0; j < 4; ++j) {
      float iv = rcpf(1.0f + ex2(-acc[0][j]));
      float fv = rcpf(1.0f + ex2(-acc[1][j]));
      float gv = 1.0f - 2.0f * rcpf(1.0f + ex2(acc[2][j]));
      float ov = rcpf(1.0f + ex2(-acc[3][j]));
      float c = fv * cs[j] + iv * gv;
      cs[j] = c;
      float th = 1.0f - 2.0f * rcpf(1.0f + ex2(c * GS_G));
      float hv = ov * th;
      hb[nxt][lk * 4 + j][hc + laneg] = f2b(hv);
    }
    bar_lds();
    cur = nxt;
  };
  for (int st = 0; st < 64; st += 2) {
    halfstep(pfA, pA, st < 62, tc0 + st * dstep, st > 0);
    halfstep(pfB, pB, st < 61, tc0 + (st + 1) * dstep, true);
  }
  store_h(tc0 + 63 * dstep);
}

// ------- fused attention + final: att = (qavg/Z) . evf ; out = in*(1+al*sig(att)) -------
__global__ __launch_bounds__(256) void k_attfin(const u16* __restrict__ VF,
                                                const float* __restrict__ qavg,
                                                const float* __restrict__ Z,
                                                const float* __restrict__ in,
                                                const float* __restrict__ alpha,
                                                float* __restrict__ out) {
  int bx = blockIdx.x;
  int b = bx >> 6;
  int sp0 = (bx & 63) << 6;
  int t = threadIdx.x, lane = t & 63, wid = t >> 6;
  __shared__ __align__(16) float lwo[256];
  __shared__ float fac[64];
  lwo[t] = qavg[b * 256 + t] / Z[b * 256 + t];
  __syncthreads();
  float4 wo = *(const float4*)&lwo[lane * 4];
  int rowbase = b * 4096 + sp0;
#pragma unroll 4
  for (int i = 0; i < 16; ++i) {
    int r = wid * 16 + i;
    uint2 v = *(const uint2*)&VF[(rowbase + r) * 256 + lane * 4];
    float x0 = b2f((u16)(v.x & 0xffff)), x1 = b2f((u16)(v.x >> 16));
    float x2 = b2f((u16)(v.y & 0xffff)), x3 = b2f((u16)(v.y >> 16));
    float p = wo.x * x0 + wo.y * x1 + wo.z * x2 + wo.w * x3;
#pragma unroll
    for (int off = 32; off; off >>= 1) p += __shfl_xor(p, off);
    if (lane == 0) fac[r] = p;
  }
  __syncthreads();
  float al = alpha[0];
  if (t < 64) fac[t] = 1.0f + al * sigf(fac[t]);
  __syncthreads();
  int sp = t & 63;
  float f = fac[sp];
  const float* ip = in + (long)b * 1048576 + sp0 + sp;
  float* op = out + (long)b * 1048576 + sp0 + sp;
  int c0 = t >> 6;
#pragma unroll 8
  for (int c = c0; c < 256; c += 4) {
    op[c * 4096] = ip[c * 4096] * f;
  }
}

extern "C" void kernel_launch(void* const* d_in, const int* in_sizes, int n_in,
                              void* d_out, int out_size, void* d_ws, size_t ws_size,
                              hipStream_t stream) {
  const float* input   = (const float*)d_in[0];
  const float* h_Wih_f = (const float*)d_in[1];
  const float* h_Whh_f = (const float*)d_in[2];
  const float* h_b_f   = (const float*)d_in[3];
  const float* h_Wih_b = (const float*)d_in[4];
  const float* h_Whh_b = (const float*)d_in[5];
  const float* h_b_b   = (const float*)d_in[6];
  const float* v_Wih_f = (const float*)d_in[7];
  const float* v_Whh_f = (const float*)d_in[8];
  const float* v_b_f   = (const float*)d_in[9];
  const float* v_Wih_b = (const float*)d_in[10];
  const float* v_Whh_b = (const float*)d_in[11];
  const float* v_b_b   = (const float*)d_in[12];
  const float* Wr      = (const float*)d_in[13];
  const float* Wl      = (const float*)d_in[14];
  const float* alphap  = (const float*)d_in[15];

  char* ws = (char*)d_ws;
  u16* Ah     = (u16*)(ws + 0);            // 33,554,432 B (also A_r)
  u16* pre    = (u16*)(ws + 33554432);     // 134,217,728 B (also VF)
  u16* Wh     = (u16*)(ws + 167772160);
  u16* Wv     = (u16*)(ws + 168296448);
  u16* WhhH   = (u16*)(ws + 168820736);
  u16* WhhV   = (u16*)(ws + 169082880);
  u16* Wrb    = (u16*)(ws + 169345024);
  float* meansum = (float*)(ws + 169476096);
  float* qavg = (float*)(ws + 169492480);
  float* pZ   = (float*)(ws + 169541632);  // 16 KB softmax denominators
  u16* Av = (u16*)d_out;
  u16* Ar = Ah;
  u16* VF = pre;

  (void)hipMemsetAsync(meansum, 0, 16 * 256 * 4, stream);
  (void)hipMemsetAsync(pZ, 0, 16 * 256 * 4, stream);

  CvtArgs ca;
  ca.src[0] = h_Wih_f; ca.dst[0] = Wh;          ca.n4[0] = 32768; ca.perm[0] = 1; ca.scl[0] = 1; ca.sh[0] = 6;
  ca.src[1] = h_Wih_b; ca.dst[1] = Wh + 131072; ca.n4[1] = 32768; ca.perm[1] = 1; ca.scl[1] = 1; ca.sh[1] = 6;
  ca.src[2] = v_Wih_f; ca.dst[2] = Wv;          ca.n4[2] = 32768; ca.perm[2] = 1; ca.scl[2] = 1; ca.sh[2] = 6;
  ca.src[3] = v_Wih_b; ca.dst[3] = Wv + 131072; ca.n4[3] = 32768; ca.perm[3] = 1; ca.scl[3] = 1; ca.sh[3] = 6;
  ca.src[4] = h_Whh_f; ca.dst[4] = WhhH;         ca.n4[4] = 16384; ca.perm[4] = 0; ca.scl[4] = 1; ca.sh[4] = 5;
  ca.src[5] = h_Whh_b; ca.dst[5] = WhhH + 65536; ca.n4[5] = 16384; ca.perm[5] = 0; ca.scl[5] = 1; ca.sh[5] = 5;
  ca.src[6] = v_Whh_f; ca.dst[6] = WhhV;         ca.n4[6] = 16384; ca.perm[6] = 0; ca.scl[6] = 1; ca.sh[6] = 5;
  ca.src[7] = v_Whh_b; ca.dst[7] = WhhV + 65536; ca.n4[7] = 16384; ca.perm[7] = 0; ca.scl[7] = 1; ca.sh[7] = 5;
  ca.src[8] = Wr;      ca.dst[8] = Wrb;          ca.n4[8] = 16384; ca.perm[8] = 0; ca.scl[8] = 2; ca.sh[8] = 6;
  k_cvt<<<dim3(128, 9), 256, 0, stream>>>(ca);

  k_tin<<<dim3(4, 64, 16), 256, 0, stream>>>(input, Ah, meansum);
  k_qavg<<<16, 256, 0, stream>>>(meansum, Wl, qavg);

  k_gemm2<<<4096, 256, 0, stream>>>(Ah, Wh, h_b_f, h_b_b, pre, 1024, 8, nullptr);
  k_recur<<<dim3(64, 2), 512, 0, stream>>>(pre, WhhH, Av);
  k_gemm2<<<4096, 256, 0, stream>>>(Av, Wv, v_b_f, v_b_b, pre, 1024, 8, nullptr);
  k_recur<<<dim3(64, 2), 512, 0, stream>>>(pre, WhhV, Ar);
  k_gemm2<<<1024, 256, 0, stream>>>(Ar, Wrb, nullptr, nullptr, VF, 256, 2, pZ);

  k_attfin<<<1024, 256, 0, stream>>>(VF, qavg, pZ, input, alphap, (float*)d_out);
}

// Round 8
// 365.462 us; speedup vs baseline: 2.5367x; 1.0708x over previous
//
#include <hip/hip_runtime.h>
#include <hip/hip_bf16.h>

typedef unsigned short u16;
typedef unsigned int u32;
typedef __attribute__((ext_vector_type(8))) short s8v;   // 8 x bf16
typedef __attribute__((ext_vector_type(4))) float f4v;   // mfma acc

__device__ __forceinline__ float b2f(u16 u) {
  union { u32 i; float f; } v; v.i = ((u32)u) << 16; return v.f;
}
__device__ __forceinline__ u16 f2b(float f) {
  union { float f; u32 i; } v; v.f = f;
  u32 r = v.i + 0x7FFFu + ((v.i >> 16) & 1u);
  return (u16)(r >> 16);
}
__device__ __forceinline__ float rcpf(float x) { return __builtin_amdgcn_rcpf(x); }
__device__ __forceinline__ float ex2(float x) {
#if __has_builtin(__builtin_amdgcn_exp2f)
  return __builtin_amdgcn_exp2f(x);
#else
  return exp2f(x);
#endif
}
__device__ __forceinline__ float sigf(float x) { return rcpf(1.0f + __expf(-x)); }

#define GS_IFO 1.4426950408889634f
#define GS_G   2.8853900817779268f

__device__ __forceinline__ void gl_lds16(const u16* g, u16* l) {
  __builtin_amdgcn_global_load_lds(
      (const __attribute__((address_space(1))) u32*)g,
      (__attribute__((address_space(3))) u32*)l, 16, 0, 0);
}

// ---------------- weight conversion fp32 -> bf16 ----------------
// scl: 0 none, 1 gate-pattern scale (exp2 domain), 2 uniform log2e. sh: log2(float4s/row).
struct CvtArgs {
  const float* src[9];
  u16* dst[9];
  int n4[9];
  int scl[9];
  int sh[9];
};
__global__ __launch_bounds__(256) void k_cvt(CvtArgs a) {
  int seg = blockIdx.y;
  int i = blockIdx.x * 256 + threadIdx.x;
  if (i >= a.n4[seg]) return;
  float4 v = ((const float4*)a.src[seg])[i];
  if (a.scl[seg]) {
    float s;
    if (a.scl[seg] == 2) {
      s = GS_IFO;
    } else {
      int r = i >> a.sh[seg];
      s = (((r >> 7) & 3) == 2) ? GS_G : GS_IFO;
    }
    v.x *= s; v.y *= s; v.z *= s; v.w *= s;
  }
  ushort4 o;
  o.x = f2b(v.x); o.y = f2b(v.y); o.z = f2b(v.z); o.w = f2b(v.w);
  ((ushort4*)a.dst[seg])[i] = o;
}

// ------- transpose input [B,C,H,W] -> A_h bf16 [(b,w,h)][c]; also channel means -------
__global__ __launch_bounds__(256) void k_tin(const float* __restrict__ in,
                                             u16* __restrict__ A,
                                             float* __restrict__ meansum) {
  int b = blockIdx.z, h = blockIdx.y, c0 = blockIdx.x * 64;
  int t = threadIdx.x, lane = t & 63, q = t >> 6;
  __shared__ u16 lT[64][66];
  const float* src = in + ((b * 256 + c0) * 64 + h) * 64;
#pragma unroll 4
  for (int i = 0; i < 16; ++i) {
    int cl = q * 16 + i;
    float v = src[cl * 4096 + lane];
    lT[cl][lane] = f2b(v);
    float s = v;
#pragma unroll
    for (int off = 32; off; off >>= 1) s += __shfl_xor(s, off);
    if (lane == 0) atomicAdd(&meansum[b * 256 + c0 + cl], s);
  }
  __syncthreads();
  u16* dst = A + (b * 4096 + h) * 256 + c0;
#pragma unroll 4
  for (int i = 0; i < 16; ++i) {
    int w = q * 16 + i;
    dst[w * 16384 + lane] = lT[lane][w];
  }
}

// ------- q_avg[b][o] = softmax_o( Wl[o,:] . mean_c ) -------
__global__ __launch_bounds__(256) void k_qavg(const float* __restrict__ meansum,
                                              const float* __restrict__ Wl,
                                              float* __restrict__ qavg) {
  int b = blockIdx.x, t = threadIdx.x;
  __shared__ float mean[256];
  __shared__ float red[256];
  mean[t] = meansum[b * 256 + t] * (1.0f / 4096.0f);
  __syncthreads();
  const float* wr = Wl + t * 256;
  float acc = 0.0f;
  for (int c = 0; c < 256; ++c) acc = fmaf(wr[c], mean[c], acc);
  red[t] = acc; __syncthreads();
  for (int s = 128; s; s >>= 1) { if (t < s) red[t] = fmaxf(red[t], red[t + s]); __syncthreads(); }
  float mx = red[0]; __syncthreads();
  float e = __expf(acc - mx);
  red[t] = e; __syncthreads();
  for (int s = 128; s; s >>= 1) { if (t < s) red[t] += red[t + s]; __syncthreads(); }
  qavg[b * 256 + t] = e / red[0];
}

// ------- 128x128-tile bf16 MFMA GEMM (only used for Wr now, with Zsum epilogue) -------
__global__ __launch_bounds__(256, 4) void k_gemm2(const u16* __restrict__ A,
                                                  const u16* __restrict__ W,
                                                  u16* __restrict__ out, int nstride, int NT,
                                                  float* __restrict__ Zsum) {
  int nwg = gridDim.x;
  int q = nwg >> 3;
  int bid = blockIdx.x;
  int swz = (bid & 7) * q + (bid >> 3);
  int mt = swz / NT, nt = swz % NT;
  int mb = mt << 7, nb = nt << 7;
  int t = threadIdx.x, lane = t & 63, wid = t >> 6;
  int laneg = lane & 15, lk = lane >> 4;
  __shared__ __align__(16) u16 lA[128][64];
  __shared__ __align__(16) u16 lW[128][64];
  f4v acc[4][4] = {};
  int wm = wid >> 1, wn = wid & 1;
  for (int kb = 0; kb < 4; ++kb) {
    if (kb) __syncthreads();
#pragma unroll
    for (int k = 0; k < 4; ++k) {
      int rb = (wid << 5) + (k << 3);
      int r = rb + (lane >> 3);
      int cs = (lane & 7) ^ (r & 7);
      const u16* ga = A + (mb + r) * 256 + (kb << 6) + (cs << 3);
      const u16* gw = W + (nb + r) * 256 + (kb << 6) + (cs << 3);
      gl_lds16(ga, &lA[rb][0]);
      gl_lds16(gw, &lW[rb][0]);
    }
    __syncthreads();
#pragma unroll
    for (int kk = 0; kk < 2; ++kk) {
      s8v af[4], bf[4];
#pragma unroll
      for (int m = 0; m < 4; ++m) {
        int r = (wm << 6) + (m << 4) + laneg;
        int c = ((kk << 2) + lk) ^ (r & 7);
        af[m] = *(const s8v*)&lA[r][c << 3];
      }
#pragma unroll
      for (int n = 0; n < 4; ++n) {
        int r = (wn << 6) + (n << 4) + laneg;
        int c = ((kk << 2) + lk) ^ (r & 7);
        bf[n] = *(const s8v*)&lW[r][c << 3];
      }
#pragma unroll
      for (int m = 0; m < 4; ++m)
#pragma unroll
        for (int n = 0; n < 4; ++n)
          acc[m][n] = __builtin_amdgcn_mfma_f32_16x16x32_bf16(af[m], bf[n], acc[m][n], 0, 0, 0);
    }
  }
#pragma unroll
  for (int n = 0; n < 4; ++n) {
    int col = nb + (wn << 6) + (n << 4) + laneg;
    float csum = 0.f;
#pragma unroll
    for (int m = 0; m < 4; ++m) {
      int row0 = mb + (wm << 6) + (m << 4) + (lk << 2);
#pragma unroll
      for (int j = 0; j < 4; ++j) {
        float e = ex2(acc[m][n][j]);
        csum += e;
        out[(row0 + j) * nstride + col] = f2b(e);
      }
    }
    csum += __shfl_xor(csum, 16);
    csum += __shfl_xor(csum, 32);
    if (lk == 0) atomicAdd(&Zsum[((mb >> 12) << 8) + col], csum);
  }
}

// ------- FUSED bidirectional LSTM: input projection (Wih.x, K=256) + recurrence -------
// X: bf16 [s*64+t][256]; Wih: [2][512][256] scaled; Whh: [2][512][128] scaled;
// outb row = (s/64)*4096 + t*64 + s%64, cols [dir*128, dir*128+128).
__global__ __launch_bounds__(512, 2) void k_recur_f(const u16* __restrict__ X,
                                                    const u16* __restrict__ Wih,
                                                    const u16* __restrict__ Whh,
                                                    const float* __restrict__ bias_f,
                                                    const float* __restrict__ bias_b,
                                                    u16* __restrict__ outb) {
  int dir = blockIdx.y;
  int s0 = blockIdx.x << 4;                 // 16 sequences per block
  int t = threadIdx.x, lane = t & 63, w = t >> 6;  // 8 waves
  int laneg = lane & 15, lk = lane >> 4;
  const u16* Wd = Whh + dir * 65536;
  const u16* Wi = Wih + dir * 131072;
  const float* bia = dir ? bias_b : bias_f;
  int hc = w << 4;
  // Whh B-fragments (K=128)
  s8v bfr[4][4];
#pragma unroll
  for (int g = 0; g < 4; ++g)
#pragma unroll
    for (int kk = 0; kk < 4; ++kk)
      bfr[g][kk] = *(const s8v*)(Wd + (g * 128 + hc + laneg) * 128 + kk * 32 + lk * 8);
  // Wih B-fragments (K=256)
  s8v ifr[4][8];
#pragma unroll
  for (int g = 0; g < 4; ++g)
#pragma unroll
    for (int kk = 0; kk < 8; ++kk)
      ifr[g][kk] = *(const s8v*)(Wi + (g * 128 + hc + laneg) * 256 + kk * 32 + lk * 8);
  float bval[4];
#pragma unroll
  for (int g = 0; g < 4; ++g)
    bval[g] = bia[g * 128 + hc + laneg] * ((g == 2) ? GS_G : GS_IFO);

  __shared__ __align__(16) u16 hb[2][16][136];
  __shared__ __align__(16) u16 xb[2][16][256];
  for (int i = t; i < 2 * 16 * 136; i += 512) ((u16*)hb)[i] = 0;

  float cs[4] = {0.f, 0.f, 0.f, 0.f};
  int tc0 = dir ? 63 : 0;
  int dstep = dir ? -1 : 1;
  // x staging: thread stages 16B of LDS row srow, chunk schunk (inverse-swizzled source)
  int srow = (w << 1) + (lane >> 5);        // 0..15
  int schunk = lane & 31;                   // 0..31 (16B chunks)
  const u16* xsrc = X + (s0 + srow) * 64 * 256 + ((schunk ^ (srow & 7)) << 3);
  int rowb = ((s0 >> 6) << 12) + (s0 & 63);
  u16* obase = outb + (dir << 7);
  // prologue: stage x(t=tc0) into xb[0]
  gl_lds16(xsrc + tc0 * 256, &xb[0][w << 1][0]);
  __syncthreads();
  int cur = 0;
  for (int st = 0; st < 64; ++st) {
    int tc = tc0 + st * dstep;
    int tn = (tc + dstep) & 63;             // clamp; garbage prefetch at st=63 unused
    // 1. store h of previous step (reads hb[cur]; writes this step go to hb[cur^1])
    if (st) {
      int pr = tc - dstep;
      uint2 hv = *(const uint2*)&hb[cur][srow][schunk << 2];
      *(uint2*)(obase + (rowb + pr * 64 + srow) * 256 + (schunk << 2)) = hv;
    }
    // 2. prefetch x(t+1) into the other buffer (drained by step-end barrier)
    gl_lds16(xsrc + tn * 256, &xb[cur ^ 1][w << 1][0]);
    // 3. MFMA: acc = bias + Wih.x + Whh.h
    f4v acc[4];
#pragma unroll
    for (int g = 0; g < 4; ++g)
      acc[g] = (f4v){bval[g], bval[g], bval[g], bval[g]};
    {
      s8v xf[4];
#pragma unroll
      for (int kk = 0; kk < 4; ++kk)
        xf[kk] = *(const s8v*)&xb[cur][laneg][((kk * 4 + lk) ^ (laneg & 7)) << 3];
#pragma unroll
      for (int g = 0; g < 4; ++g)
#pragma unroll
        for (int kk = 0; kk < 4; ++kk)
          acc[g] = __builtin_amdgcn_mfma_f32_16x16x32_bf16(xf[kk], ifr[g][kk], acc[g], 0, 0, 0);
#pragma unroll
      for (int kk = 0; kk < 4; ++kk)
        xf[kk] = *(const s8v*)&xb[cur][laneg][(((kk + 4) * 4 + lk) ^ (laneg & 7)) << 3];
#pragma unroll
      for (int g = 0; g < 4; ++g)
#pragma unroll
        for (int kk = 0; kk < 4; ++kk)
          acc[g] = __builtin_amdgcn_mfma_f32_16x16x32_bf16(xf[kk], ifr[g][kk + 4], acc[g], 0, 0, 0);
    }
    {
      s8v afr[4];
#pragma unroll
      for (int kk = 0; kk < 4; ++kk)
        afr[kk] = *(const s8v*)&hb[cur][laneg][kk * 32 + lk * 8];
#pragma unroll
      for (int g = 0; g < 4; ++g)
#pragma unroll
        for (int kk = 0; kk < 4; ++kk)
          acc[g] = __builtin_amdgcn_mfma_f32_16x16x32_bf16(afr[kk], bfr[g][kk], acc[g], 0, 0, 0);
    }
    // 4. gates
    int nxt = cur ^ 1;
#pragma unroll
    for (int j = 0; j < 4; ++j) {
      float iv = rcpf(1.0f + ex2(-acc[0][j]));
      float fv = rcpf(1.0f + ex2(-acc[1][j]));
      float gv = 1.0f - 2.0f * rcpf(1.0f + ex2(acc[2][j]));
      float ov = rcpf(1.0f + ex2(-acc[3][j]));
      float c = fv * cs[j] + iv * gv;
      cs[j] = c;
      float th = 1.0f - 2.0f * rcpf(1.0f + ex2(c * GS_G));
      hb[nxt][lk * 4 + j][hc + laneg] = f2b(ov * th);
    }
    __syncthreads();
    cur = nxt;
  }
  // final h store
  {
    int pr = tc0 + 63 * dstep;
    uint2 hv = *(const uint2*)&hb[cur][srow][schunk << 2];
    *(uint2*)(obase + (rowb + pr * 64 + srow) * 256 + (schunk << 2)) = hv;
  }
}

// ------- fused attention + final: att = (qavg/Z) . evf ; out = in*(1+al*sig(att)) -------
__global__ __launch_bounds__(256) void k_attfin(const u16* __restrict__ VF,
                                                const float* __restrict__ qavg,
                                                const float* __restrict__ Z,
                                                const float* __restrict__ in,
                                                const float* __restrict__ alpha,
                                                float* __restrict__ out) {
  int bx = blockIdx.x;
  int b = bx >> 6;
  int sp0 = (bx & 63) << 6;
  int t = threadIdx.x, lane = t & 63, wid = t >> 6;
  __shared__ __align__(16) float lwo[256];
  __shared__ float fac[64];
  lwo[t] = qavg[b * 256 + t] / Z[b * 256 + t];
  __syncthreads();
  float4 wo = *(const float4*)&lwo[lane * 4];
  int rowbase = b * 4096 + sp0;
#pragma unroll 4
  for (int i = 0; i < 16; ++i) {
    int r = wid * 16 + i;
    uint2 v = *(const uint2*)&VF[(rowbase + r) * 256 + lane * 4];
    float x0 = b2f((u16)(v.x & 0xffff)), x1 = b2f((u16)(v.x >> 16));
    float x2 = b2f((u16)(v.y & 0xffff)), x3 = b2f((u16)(v.y >> 16));
    float p = wo.x * x0 + wo.y * x1 + wo.z * x2 + wo.w * x3;
#pragma unroll
    for (int off = 32; off; off >>= 1) p += __shfl_xor(p, off);
    if (lane == 0) fac[r] = p;
  }
  __syncthreads();
  float al = alpha[0];
  if (t < 64) fac[t] = 1.0f + al * sigf(fac[t]);
  __syncthreads();
  int sp = t & 63;
  float f = fac[sp];
  const float* ip = in + (long)b * 1048576 + sp0 + sp;
  float* op = out + (long)b * 1048576 + sp0 + sp;
  int c0 = t >> 6;
#pragma unroll 8
  for (int c = c0; c < 256; c += 4) {
    op[c * 4096] = ip[c * 4096] * f;
  }
}

extern "C" void kernel_launch(void* const* d_in, const int* in_sizes, int n_in,
                              void* d_out, int out_size, void* d_ws, size_t ws_size,
                              hipStream_t stream) {
  const float* input   = (const float*)d_in[0];
  const float* h_Wih_f = (const float*)d_in[1];
  const float* h_Whh_f = (const float*)d_in[2];
  const float* h_b_f   = (const float*)d_in[3];
  const float* h_Wih_b = (const float*)d_in[4];
  const float* h_Whh_b = (const float*)d_in[5];
  const float* h_b_b   = (const float*)d_in[6];
  const float* v_Wih_f = (const float*)d_in[7];
  const float* v_Whh_f = (const float*)d_in[8];
  const float* v_b_f   = (const float*)d_in[9];
  const float* v_Wih_b = (const float*)d_in[10];
  const float* v_Whh_b = (const float*)d_in[11];
  const float* v_b_b   = (const float*)d_in[12];
  const float* Wr      = (const float*)d_in[13];
  const float* Wl      = (const float*)d_in[14];
  const float* alphap  = (const float*)d_in[15];

  char* ws = (char*)d_ws;
  u16* Ah     = (u16*)(ws + 0);            // 33,554,432 B  (x for horizontal; later Ar)
  u16* VF     = (u16*)(ws + 33554432);     // 33,554,432 B
  u16* Wh     = (u16*)(ws + 167772160);    // [2][512][256] bf16
  u16* Wv     = (u16*)(ws + 168296448);    // [2][512][256]
  u16* WhhH   = (u16*)(ws + 168820736);    // [2][512][128]
  u16* WhhV   = (u16*)(ws + 169082880);
  u16* Wrb    = (u16*)(ws + 169345024);    // [256][256]
  float* meansum = (float*)(ws + 169476096);
  float* qavg = (float*)(ws + 169492480);
  float* pZ   = (float*)(ws + 169541632);  // 16 KB softmax denominators
  u16* Av = (u16*)d_out;                   // horizontal biLSTM output (33.5 MB < 64 MB)
  u16* Ar = Ah;

  (void)hipMemsetAsync(meansum, 0, 16 * 256 * 4, stream);
  (void)hipMemsetAsync(pZ, 0, 16 * 256 * 4, stream);

  CvtArgs ca;
  ca.src[0] = h_Wih_f; ca.dst[0] = Wh;          ca.n4[0] = 32768; ca.scl[0] = 1; ca.sh[0] = 6;
  ca.src[1] = h_Wih_b; ca.dst[1] = Wh + 131072; ca.n4[1] = 32768; ca.scl[1] = 1; ca.sh[1] = 6;
  ca.src[2] = v_Wih_f; ca.dst[2] = Wv;          ca.n4[2] = 32768; ca.scl[2] = 1; ca.sh[2] = 6;
  ca.src[3] = v_Wih_b; ca.dst[3] = Wv + 131072; ca.n4[3] = 32768; ca.scl[3] = 1; ca.sh[3] = 6;
  ca.src[4] = h_Whh_f; ca.dst[4] = WhhH;         ca.n4[4] = 16384; ca.scl[4] = 1; ca.sh[4] = 5;
  ca.src[5] = h_Whh_b; ca.dst[5] = WhhH + 65536; ca.n4[5] = 16384; ca.scl[5] = 1; ca.sh[5] = 5;
  ca.src[6] = v_Whh_f; ca.dst[6] = WhhV;         ca.n4[6] = 16384; ca.scl[6] = 1; ca.sh[6] = 5;
  ca.src[7] = v_Whh_b; ca.dst[7] = WhhV + 65536; ca.n4[7] = 16384; ca.scl[7] = 1; ca.sh[7] = 5;
  ca.src[8] = Wr;      ca.dst[8] = Wrb;          ca.n4[8] = 16384; ca.scl[8] = 2; ca.sh[8] = 6;
  k_cvt<<<dim3(128, 9), 256, 0, stream>>>(ca);

  k_tin<<<dim3(4, 64, 16), 256, 0, stream>>>(input, Ah, meansum);
  k_qavg<<<16, 256, 0, stream>>>(meansum, Wl, qavg);

  k_recur_f<<<dim3(64, 2), 512, 0, stream>>>(Ah, Wh, WhhH, h_b_f, h_b_b, Av);
  k_recur_f<<<dim3(64, 2), 512, 0, stream>>>(Av, Wv, WhhV, v_b_f, v_b_b, Ar);
  k_gemm2<<<1024, 256, 0, stream>>>(Ar, Wrb, VF, 256, 2, pZ);

  k_attfin<<<1024, 256, 0, stream>>>(VF, qavg, pZ, input, alphap, (float*)d_out);
}

// Round 9
// 363.551 us; speedup vs baseline: 2.5500x; 1.0053x over previous
//
#include <hip/hip_runtime.h>
#include <hip/hip_bf16.h>

typedef unsigned short u16;
typedef unsigned int u32;
typedef __attribute__((ext_vector_type(8))) short s8v;   // 8 x bf16
typedef __attribute__((ext_vector_type(4))) float f4v;   // mfma acc

__device__ __forceinline__ float b2f(u16 u) {
  union { u32 i; float f; } v; v.i = ((u32)u) << 16; return v.f;
}
__device__ __forceinline__ u16 f2b(float f) {
  union { float f; u32 i; } v; v.f = f;
  u32 r = v.i + 0x7FFFu + ((v.i >> 16) & 1u);
  return (u16)(r >> 16);
}
__device__ __forceinline__ float rcpf(float x) { return __builtin_amdgcn_rcpf(x); }
__device__ __forceinline__ float ex2(float x) {
#if __has_builtin(__builtin_amdgcn_exp2f)
  return __builtin_amdgcn_exp2f(x);
#else
  return exp2f(x);
#endif
}
__device__ __forceinline__ float sigf(float x) { return rcpf(1.0f + __expf(-x)); }

#define GS_IFO 1.4426950408889634f
#define GS_G   2.8853900817779268f

__device__ __forceinline__ void gl_lds16(const u16* g, u16* l) {
  __builtin_amdgcn_global_load_lds(
      (const __attribute__((address_space(1))) u32*)g,
      (__attribute__((address_space(3))) u32*)l, 16, 0, 0);
}

// ---------------- weight conversion fp32 -> bf16 ----------------
// scl: 0 none, 1 gate-pattern scale (exp2 domain), 2 uniform log2e. sh: log2(float4s/row).
struct CvtArgs {
  const float* src[9];
  u16* dst[9];
  int n4[9];
  int scl[9];
  int sh[9];
};
__global__ __launch_bounds__(256) void k_cvt(CvtArgs a) {
  int seg = blockIdx.y;
  int i = blockIdx.x * 256 + threadIdx.x;
  if (i >= a.n4[seg]) return;
  float4 v = ((const float4*)a.src[seg])[i];
  if (a.scl[seg]) {
    float s;
    if (a.scl[seg] == 2) {
      s = GS_IFO;
    } else {
      int r = i >> a.sh[seg];
      s = (((r >> 7) & 3) == 2) ? GS_G : GS_IFO;
    }
    v.x *= s; v.y *= s; v.z *= s; v.w *= s;
  }
  ushort4 o;
  o.x = f2b(v.x); o.y = f2b(v.y); o.z = f2b(v.z); o.w = f2b(v.w);
  ((ushort4*)a.dst[seg])[i] = o;
}

// ------- transpose input [B,C,H,W] -> A_h bf16 [(b,w,h)][c]; also channel means -------
__global__ __launch_bounds__(256) void k_tin(const float* __restrict__ in,
                                             u16* __restrict__ A,
                                             float* __restrict__ meansum) {
  int b = blockIdx.z, h = blockIdx.y, c0 = blockIdx.x * 64;
  int t = threadIdx.x, lane = t & 63, q = t >> 6;
  __shared__ u16 lT[64][66];
  const float* src = in + ((b * 256 + c0) * 64 + h) * 64;
#pragma unroll 4
  for (int i = 0; i < 16; ++i) {
    int cl = q * 16 + i;
    float v = src[cl * 4096 + lane];
    lT[cl][lane] = f2b(v);
    float s = v;
#pragma unroll
    for (int off = 32; off; off >>= 1) s += __shfl_xor(s, off);
    if (lane == 0) atomicAdd(&meansum[b * 256 + c0 + cl], s);
  }
  __syncthreads();
  u16* dst = A + (b * 4096 + h) * 256 + c0;
#pragma unroll 4
  for (int i = 0; i < 16; ++i) {
    int w = q * 16 + i;
    dst[w * 16384 + lane] = lT[lane][w];
  }
}

// ------- q_avg[b][o] = softmax_o( Wl[o,:] . mean_c ) -------
__global__ __launch_bounds__(256) void k_qavg(const float* __restrict__ meansum,
                                              const float* __restrict__ Wl,
                                              float* __restrict__ qavg) {
  int b = blockIdx.x, t = threadIdx.x;
  __shared__ float mean[256];
  __shared__ float red[256];
  mean[t] = meansum[b * 256 + t] * (1.0f / 4096.0f);
  __syncthreads();
  const float* wr = Wl + t * 256;
  float acc = 0.0f;
  for (int c = 0; c < 256; ++c) acc = fmaf(wr[c], mean[c], acc);
  red[t] = acc; __syncthreads();
  for (int s = 128; s; s >>= 1) { if (t < s) red[t] = fmaxf(red[t], red[t + s]); __syncthreads(); }
  float mx = red[0]; __syncthreads();
  float e = __expf(acc - mx);
  red[t] = e; __syncthreads();
  for (int s = 128; s; s >>= 1) { if (t < s) red[t] += red[t + s]; __syncthreads(); }
  qavg[b * 256 + t] = e / red[0];
}

// ------- 128x128-tile bf16 MFMA GEMM (only used for Wr now, with Zsum epilogue) -------
__global__ __launch_bounds__(256, 4) void k_gemm2(const u16* __restrict__ A,
                                                  const u16* __restrict__ W,
                                                  u16* __restrict__ out, int nstride, int NT,
                                                  float* __restrict__ Zsum) {
  int nwg = gridDim.x;
  int q = nwg >> 3;
  int bid = blockIdx.x;
  int swz = (bid & 7) * q + (bid >> 3);
  int mt = swz / NT, nt = swz % NT;
  int mb = mt << 7, nb = nt << 7;
  int t = threadIdx.x, lane = t & 63, wid = t >> 6;
  int laneg = lane & 15, lk = lane >> 4;
  __shared__ __align__(16) u16 lA[128][64];
  __shared__ __align__(16) u16 lW[128][64];
  f4v acc[4][4] = {};
  int wm = wid >> 1, wn = wid & 1;
  for (int kb = 0; kb < 4; ++kb) {
    if (kb) __syncthreads();
#pragma unroll
    for (int k = 0; k < 4; ++k) {
      int rb = (wid << 5) + (k << 3);
      int r = rb + (lane >> 3);
      int cs = (lane & 7) ^ (r & 7);
      const u16* ga = A + (mb + r) * 256 + (kb << 6) + (cs << 3);
      const u16* gw = W + (nb + r) * 256 + (kb << 6) + (cs << 3);
      gl_lds16(ga, &lA[rb][0]);
      gl_lds16(gw, &lW[rb][0]);
    }
    __syncthreads();
#pragma unroll
    for (int kk = 0; kk < 2; ++kk) {
      s8v af[4], bf[4];
#pragma unroll
      for (int m = 0; m < 4; ++m) {
        int r = (wm << 6) + (m << 4) + laneg;
        int c = ((kk << 2) + lk) ^ (r & 7);
        af[m] = *(const s8v*)&lA[r][c << 3];
      }
#pragma unroll
      for (int n = 0; n < 4; ++n) {
        int r = (wn << 6) + (n << 4) + laneg;
        int c = ((kk << 2) + lk) ^ (r & 7);
        bf[n] = *(const s8v*)&lW[r][c << 3];
      }
#pragma unroll
      for (int m = 0; m < 4; ++m)
#pragma unroll
        for (int n = 0; n < 4; ++n)
          acc[m][n] = __builtin_amdgcn_mfma_f32_16x16x32_bf16(af[m], bf[n], acc[m][n], 0, 0, 0);
    }
  }
#pragma unroll
  for (int n = 0; n < 4; ++n) {
    int col = nb + (wn << 6) + (n << 4) + laneg;
    float csum = 0.f;
#pragma unroll
    for (int m = 0; m < 4; ++m) {
      int row0 = mb + (wm << 6) + (m << 4) + (lk << 2);
#pragma unroll
      for (int j = 0; j < 4; ++j) {
        float e = ex2(acc[m][n][j]);
        csum += e;
        out[(row0 + j) * nstride + col] = f2b(e);
      }
    }
    csum += __shfl_xor(csum, 16);
    csum += __shfl_xor(csum, 32);
    if (lk == 0) atomicAdd(&Zsum[((mb >> 12) << 8) + col], csum);
  }
}

// ------- FUSED bidirectional LSTM: input projection (Wih.x, K=256) + recurrence.
// v2: 3-buffer x prefetch (distance 2) + counted-vmcnt barrier (stores stay in flight). -------
__global__ __launch_bounds__(512, 2) void k_recur_f(const u16* __restrict__ X,
                                                    const u16* __restrict__ Wih,
                                                    const u16* __restrict__ Whh,
                                                    const float* __restrict__ bias_f,
                                                    const float* __restrict__ bias_b,
                                                    u16* __restrict__ outb) {
  int dir = blockIdx.y;
  int s0 = blockIdx.x << 4;                 // 16 sequences per block
  int t = threadIdx.x, lane = t & 63, w = t >> 6;  // 8 waves
  int laneg = lane & 15, lk = lane >> 4;
  const u16* Wd = Whh + dir * 65536;
  const u16* Wi = Wih + dir * 131072;
  const float* bia = dir ? bias_b : bias_f;
  int hc = w << 4;
  // Whh B-fragments (K=128)
  s8v bfr[4][4];
#pragma unroll
  for (int g = 0; g < 4; ++g)
#pragma unroll
    for (int kk = 0; kk < 4; ++kk)
      bfr[g][kk] = *(const s8v*)(Wd + (g * 128 + hc + laneg) * 128 + kk * 32 + lk * 8);
  // Wih B-fragments (K=256)
  s8v ifr[4][8];
#pragma unroll
  for (int g = 0; g < 4; ++g)
#pragma unroll
    for (int kk = 0; kk < 8; ++kk)
      ifr[g][kk] = *(const s8v*)(Wi + (g * 128 + hc + laneg) * 256 + kk * 32 + lk * 8);
  float bval[4];
#pragma unroll
  for (int g = 0; g < 4; ++g)
    bval[g] = bia[g * 128 + hc + laneg] * ((g == 2) ? GS_G : GS_IFO);

  __shared__ __align__(16) u16 hb[2][16][136];
  __shared__ __align__(16) u16 xb[3][16][256];
  for (int i = t; i < 2 * 16 * 136; i += 512) ((u16*)hb)[i] = 0;

  float cs[4] = {0.f, 0.f, 0.f, 0.f};
  int tc0 = dir ? 63 : 0;
  int dstep = dir ? -1 : 1;
  // x staging: thread stages 16B of LDS row srow, chunk schunk (inverse-swizzled source)
  int srow = (w << 1) + (lane >> 5);        // 0..15
  int schunk = lane & 31;                   // 0..31 (16B chunks)
  const u16* xsrc = X + (s0 + srow) * 64 * 256 + ((schunk ^ (srow & 7)) << 3);
  int rowb = ((s0 >> 6) << 12) + (s0 & 63);
  u16* obase = outb + (dir << 7);
  // prologue: stage x(t0) -> xb[0], x(t0+1) -> xb[1]; full drain once.
  gl_lds16(xsrc + tc0 * 256, &xb[0][w << 1][0]);
  gl_lds16(xsrc + ((tc0 + dstep) & 63) * 256, &xb[1][w << 1][0]);
  __syncthreads();
  int cur = 0;
  for (int st = 0; st < 64; ++st) {
    int tc = tc0 + st * dstep;
    // 1. store h of previous step (reads hb[cur]; this step's writes go to hb[cur^1])
    if (st) {
      int pr = tc - dstep;
      uint2 hv = *(const uint2*)&hb[cur][srow][schunk << 2];
      *(uint2*)(obase + (rowb + pr * 64 + srow) * 256 + (schunk << 2)) = hv;
    }
    // 2. prefetch x(t+2) into xb[(st+2)%3] (consumed at step st+2; buffer free since st-1)
    {
      int tn = (tc0 + (st + 2) * dstep) & 63;   // wraps at tail; garbage unused
      gl_lds16(xsrc + tn * 256, &xb[(st + 2) % 3][w << 1][0]);
    }
    // 3. MFMA: acc = bias + Wih.x_t + Whh.h
    f4v acc[4];
#pragma unroll
    for (int g = 0; g < 4; ++g)
      acc[g] = (f4v){bval[g], bval[g], bval[g], bval[g]};
    {
      const u16* xrow = &xb[st % 3][laneg][0];
      s8v xf[4];
#pragma unroll
      for (int kk = 0; kk < 4; ++kk)
        xf[kk] = *(const s8v*)&xrow[((kk * 4 + lk) ^ (laneg & 7)) << 3];
#pragma unroll
      for (int g = 0; g < 4; ++g)
#pragma unroll
        for (int kk = 0; kk < 4; ++kk)
          acc[g] = __builtin_amdgcn_mfma_f32_16x16x32_bf16(xf[kk], ifr[g][kk], acc[g], 0, 0, 0);
#pragma unroll
      for (int kk = 0; kk < 4; ++kk)
        xf[kk] = *(const s8v*)&xrow[(((kk + 4) * 4 + lk) ^ (laneg & 7)) << 3];
#pragma unroll
      for (int g = 0; g < 4; ++g)
#pragma unroll
        for (int kk = 0; kk < 4; ++kk)
          acc[g] = __builtin_amdgcn_mfma_f32_16x16x32_bf16(xf[kk], ifr[g][kk + 4], acc[g], 0, 0, 0);
    }
    {
      s8v afr[4];
#pragma unroll
      for (int kk = 0; kk < 4; ++kk)
        afr[kk] = *(const s8v*)&hb[cur][laneg][kk * 32 + lk * 8];
#pragma unroll
      for (int g = 0; g < 4; ++g)
#pragma unroll
        for (int kk = 0; kk < 4; ++kk)
          acc[g] = __builtin_amdgcn_mfma_f32_16x16x32_bf16(afr[kk], bfr[g][kk], acc[g], 0, 0, 0);
    }
    // 4. gates
    int nxt = cur ^ 1;
#pragma unroll
    for (int j = 0; j < 4; ++j) {
      float iv = rcpf(1.0f + ex2(-acc[0][j]));
      float fv = rcpf(1.0f + ex2(-acc[1][j]));
      float gv = 1.0f - 2.0f * rcpf(1.0f + ex2(acc[2][j]));
      float ov = rcpf(1.0f + ex2(-acc[3][j]));
      float c = fv * cs[j] + iv * gv;
      cs[j] = c;
      float th = 1.0f - 2.0f * rcpf(1.0f + ex2(c * GS_G));
      hb[nxt][lk * 4 + j][hc + laneg] = f2b(ov * th);
    }
    // 5. counted barrier: own ds ops done; gl_lds(t+1) done (2 newer VMEM ops may fly:
    //    this step's h-store + this step's gl_lds(t+2)). Store-acks never drained.
    asm volatile("s_waitcnt lgkmcnt(0) vmcnt(2)" ::: "memory");
    __builtin_amdgcn_s_barrier();
    cur = nxt;
  }
  // final h store
  {
    int pr = tc0 + 63 * dstep;
    uint2 hv = *(const uint2*)&hb[cur][srow][schunk << 2];
    *(uint2*)(obase + (rowb + pr * 64 + srow) * 256 + (schunk << 2)) = hv;
  }
}

// ------- fused attention + final: att = (qavg/Z) . evf ; out = in*(1+al*sig(att)) -------
__global__ __launch_bounds__(256) void k_attfin(const u16* __restrict__ VF,
                                                const float* __restrict__ qavg,
                                                const float* __restrict__ Z,
                                                const float* __restrict__ in,
                                                const float* __restrict__ alpha,
                                                float* __restrict__ out) {
  int bx = blockIdx.x;
  int b = bx >> 6;
  int sp0 = (bx & 63) << 6;
  int t = threadIdx.x, lane = t & 63, wid = t >> 6;
  __shared__ __align__(16) float lwo[256];
  __shared__ float fac[64];
  lwo[t] = qavg[b * 256 + t] / Z[b * 256 + t];
  __syncthreads();
  float4 wo = *(const float4*)&lwo[lane * 4];
  int rowbase = b * 4096 + sp0;
#pragma unroll 4
  for (int i = 0; i < 16; ++i) {
    int r = wid * 16 + i;
    uint2 v = *(const uint2*)&VF[(rowbase + r) * 256 + lane * 4];
    float x0 = b2f((u16)(v.x & 0xffff)), x1 = b2f((u16)(v.x >> 16));
    float x2 = b2f((u16)(v.y & 0xffff)), x3 = b2f((u16)(v.y >> 16));
    float p = wo.x * x0 + wo.y * x1 + wo.z * x2 + wo.w * x3;
#pragma unroll
    for (int off = 32; off; off >>= 1) p += __shfl_xor(p, off);
    if (lane == 0) fac[r] = p;
  }
  __syncthreads();
  float al = alpha[0];
  if (t < 64) fac[t] = 1.0f + al * sigf(fac[t]);
  __syncthreads();
  int sp = t & 63;
  float f = fac[sp];
  const float* ip = in + (long)b * 1048576 + sp0 + sp;
  float* op = out + (long)b * 1048576 + sp0 + sp;
  int c0 = t >> 6;
#pragma unroll 8
  for (int c = c0; c < 256; c += 4) {
    op[c * 4096] = ip[c * 4096] * f;
  }
}

extern "C" void kernel_launch(void* const* d_in, const int* in_sizes, int n_in,
                              void* d_out, int out_size, void* d_ws, size_t ws_size,
                              hipStream_t stream) {
  const float* input   = (const float*)d_in[0];
  const float* h_Wih_f = (const float*)d_in[1];
  const float* h_Whh_f = (const float*)d_in[2];
  const float* h_b_f   = (const float*)d_in[3];
  const float* h_Wih_b = (const float*)d_in[4];
  const float* h_Whh_b = (const float*)d_in[5];
  const float* h_b_b   = (const float*)d_in[6];
  const float* v_Wih_f = (const float*)d_in[7];
  const float* v_Whh_f = (const float*)d_in[8];
  const float* v_b_f   = (const float*)d_in[9];
  const float* v_Wih_b = (const float*)d_in[10];
  const float* v_Whh_b = (const float*)d_in[11];
  const float* v_b_b   = (const float*)d_in[12];
  const float* Wr      = (const float*)d_in[13];
  const float* Wl      = (const float*)d_in[14];
  const float* alphap  = (const float*)d_in[15];

  char* ws = (char*)d_ws;
  u16* Ah     = (u16*)(ws + 0);            // 33,554,432 B  (x for horizontal; later Ar)
  u16* VF     = (u16*)(ws + 33554432);     // 33,554,432 B
  u16* Wh     = (u16*)(ws + 167772160);    // [2][512][256] bf16
  u16* Wv     = (u16*)(ws + 168296448);    // [2][512][256]
  u16* WhhH   = (u16*)(ws + 168820736);    // [2][512][128]
  u16* WhhV   = (u16*)(ws + 169082880);
  u16* Wrb    = (u16*)(ws + 169345024);    // [256][256]
  float* meansum = (float*)(ws + 169476096);
  float* qavg = (float*)(ws + 169492480);
  float* pZ   = (float*)(ws + 169541632);  // 16 KB softmax denominators
  u16* Av = (u16*)d_out;                   // horizontal biLSTM output (33.5 MB < 64 MB)
  u16* Ar = Ah;

  (void)hipMemsetAsync(meansum, 0, 16 * 256 * 4, stream);
  (void)hipMemsetAsync(pZ, 0, 16 * 256 * 4, stream);

  CvtArgs ca;
  ca.src[0] = h_Wih_f; ca.dst[0] = Wh;          ca.n4[0] = 32768; ca.scl[0] = 1; ca.sh[0] = 6;
  ca.src[1] = h_Wih_b; ca.dst[1] = Wh + 131072; ca.n4[1] = 32768; ca.scl[1] = 1; ca.sh[1] = 6;
  ca.src[2] = v_Wih_f; ca.dst[2] = Wv;          ca.n4[2] = 32768; ca.scl[2] = 1; ca.sh[2] = 6;
  ca.src[3] = v_Wih_b; ca.dst[3] = Wv + 131072; ca.n4[3] = 32768; ca.scl[3] = 1; ca.sh[3] = 6;
  ca.src[4] = h_Whh_f; ca.dst[4] = WhhH;         ca.n4[4] = 16384; ca.scl[4] = 1; ca.sh[4] = 5;
  ca.src[5] = h_Whh_b; ca.dst[5] = WhhH + 65536; ca.n4[5] = 16384; ca.scl[5] = 1; ca.sh[5] = 5;
  ca.src[6] = v_Whh_f; ca.dst[6] = WhhV;         ca.n4[6] = 16384; ca.scl[6] = 1; ca.sh[6] = 5;
  ca.src[7] = v_Whh_b; ca.dst[7] = WhhV + 65536; ca.n4[7] = 16384; ca.scl[7] = 1; ca.sh[7] = 5;
  ca.src[8] = Wr;      ca.dst[8] = Wrb;          ca.n4[8] = 16384; ca.scl[8] = 2; ca.sh[8] = 6;
  k_cvt<<<dim3(128, 9), 256, 0, stream>>>(ca);

  k_tin<<<dim3(4, 64, 16), 256, 0, stream>>>(input, Ah, meansum);
  k_qavg<<<16, 256, 0, stream>>>(meansum, Wl, qavg);

  k_recur_f<<<dim3(64, 2), 512, 0, stream>>>(Ah, Wh, WhhH, h_b_f, h_b_b, Av);
  k_recur_f<<<dim3(64, 2), 512, 0, stream>>>(Av, Wv, WhhV, v_b_f, v_b_b, Ar);
  k_gemm2<<<1024, 256, 0, stream>>>(Ar, Wrb, VF, 256, 2, pZ);

  k_attfin<<<1024, 256, 0, stream>>>(VF, qavg, pZ, input, alphap, (float*)d_out);
}